// Round 2
// baseline (6753.495 us; speedup 1.0000x reference)
//
#include <hip/hip_runtime.h>
#include <math.h>

// ---------------- workspace layout (float indices) ----------------
#define WS_OFF_U     0        // 4032 used, pad to 4096
#define WS_OFF_T     4096     // 2304 (t vectors, zeroed)
#define WS_OFF_TN    6400     // 6 (+2 pad)  ||t||^2 per layer (zeroed)
#define WS_OFF_S2    6408     // 6 (+2 pad)  ||M t||^2 per layer (zeroed)
#define WS_OFF_BBOX  6416     // 256 ints (64 tuples x {x0,h,y0,w})
#define WS_OFF_W     8192     // 3,144,384 scaled weights
#define WS_OFF_C     3152896  // 2,097,152 out_8 normalized
#define WS_OFF_D     5250048  // 1,048,576 out_16 normalized
// total ~6.3M floats (~25.2 MB)

// ---------------- d_out layout (float offsets) ----------------
// NOTE: the 1x1 convs in the reference ALSO get padding (1,1) -> 18x18 / 34x34!
#define OUT_X    0          // 8*2048*8*8     = 1,048,576
#define OUT_X1   1048576    // 8*2048*18*18   = 5,308,416
#define OUT_X2   6356992    // 8*2048*34*34   = 18,939,904 (also hosts bufA/bufB scratch)
#define OUT_IMG  25296896   // 8*24*256*256   = 12,582,912
// total 37,879,808 floats

struct Ptr6 { const float* p[6]; };

// =================== MT19937 + legacy gauss (numpy RandomState) ===================
__device__ __forceinline__ unsigned int mt_next(unsigned int* mt, int& pos){
  if (pos >= 624){
    for (int i = 0; i < 624; i++){
      unsigned int y = (mt[i] & 0x80000000u) | (mt[(i+1)%624] & 0x7fffffffu);
      mt[i] = mt[(i+397)%624] ^ (y >> 1) ^ ((y & 1u) ? 0x9908b0dfu : 0u);
    }
    pos = 0;
  }
  unsigned int y = mt[pos++];
  y ^= y >> 11;
  y ^= (y << 7)  & 0x9d2c5680u;
  y ^= (y << 15) & 0xefc60000u;
  y ^= y >> 18;
  return y;
}
__device__ __forceinline__ double mt_double(unsigned int* mt, int& pos){
  unsigned int a = mt_next(mt, pos) >> 5;
  unsigned int b = mt_next(mt, pos) >> 6;
  return (a * 67108864.0 + b) / 9007199254740992.0;
}

__global__ void gen_u_kernel(float* ws){
  int l = threadIdx.x;
  if (l >= 6) return;
  const int os[6]   = {64,128,256,512,1024,2048};
  const int uoff[6] = {0,64,192,448,960,1984};
  unsigned int mt[624];
  unsigned int seed = (unsigned int)(l + 1);
  for (int i = 0; i < 624; i++){
    mt[i] = seed;
    seed = 1812433253u * (seed ^ (seed >> 30)) + (unsigned int)(i + 1);
  }
  int pos = 624;
  float* u = ws + WS_OFF_U + uoff[l];
  int n = os[l];
  bool has = false; double gcache = 0.0;
  for (int i = 0; i < n; i++){
    double val;
    if (has){ val = gcache; has = false; }
    else {
      double x1, x2, r2;
      do {
        x1 = 2.0 * mt_double(mt, pos) - 1.0;
        x2 = 2.0 * mt_double(mt, pos) - 1.0;
        r2 = x1*x1 + x2*x2;
      } while (r2 >= 1.0 || r2 == 0.0);
      double f = sqrt(-2.0 * log(r2) / r2);
      gcache = f * x1; has = true; val = f * x2;
    }
    u[i] = (float)val;
  }
}

// =================== spectral norm: t = M^T u (atomic partial) ===================
__global__ void sn_t_kernel(Ptr6 wp, float* ws){
  const int o[6]    = {64,128,256,512,1024,2048};
  const int cols[6] = {27,72,144,288,576,1152};
  const int uoff[6] = {0,64,192,448,960,1984};
  const int toff[6] = {0,27,99,243,531,1107};
  const int bstart[7] = {0,1,2,4,8,16,32};
  int b = blockIdx.x;
  int l = 0; while (l < 5 && b >= bstart[l+1]) l++;
  int chunk = b - bstart[l];
  int r0 = chunk * 128;
  int r1 = min(r0 + 128, o[l]);
  const float* m = wp.p[l];
  const float* u = ws + WS_OFF_U + uoff[l];
  float* t = ws + WS_OFF_T + toff[l];
  int C = cols[l];
  for (int j = threadIdx.x; j < C; j += blockDim.x){
    float acc = 0.f;
    for (int r = r0; r < r1; r++) acc += m[(size_t)r * C + j] * u[r];
    atomicAdd(&t[j], acc);
  }
}

__global__ void sn_tn_kernel(float* ws){
  const int cols[6] = {27,72,144,288,576,1152};
  const int toff[6] = {0,27,99,243,531,1107};
  int l = blockIdx.x;
  const float* t = ws + WS_OFF_T + toff[l];
  float s = 0.f;
  for (int j = threadIdx.x; j < cols[l]; j += 256){ float v = t[j]; s += v*v; }
  __shared__ float sb[4];
  int lane = threadIdx.x & 63, wid = threadIdx.x >> 6;
  for (int o = 32; o; o >>= 1) s += __shfl_down(s, o, 64);
  if (lane == 0) sb[wid] = s;
  __syncthreads();
  if (threadIdx.x == 0) ws[WS_OFF_TN + l] = sb[0] + sb[1] + sb[2] + sb[3];
}

__global__ void sn_sig_kernel(Ptr6 wp, float* ws){
  const int o[6]    = {64,128,256,512,1024,2048};
  const int cols[6] = {27,72,144,288,576,1152};
  const int toff[6] = {0,27,99,243,531,1107};
  const int bstart[7] = {0,1,2,3,5,9,17};
  int b = blockIdx.x;
  int l = 0; while (l < 5 && b >= bstart[l+1]) l++;
  int chunk = b - bstart[l];
  int r0 = chunk * 256;
  int r1 = min(r0 + 256, o[l]);
  int C = cols[l];
  __shared__ float ts[1152];
  const float* t = ws + WS_OFF_T + toff[l];
  for (int j = threadIdx.x; j < C; j += 256) ts[j] = t[j];
  __syncthreads();
  float zsq = 0.f;
  int r = r0 + (int)threadIdx.x;
  if (r < r1){
    const float* m = wp.p[l] + (size_t)r * C;
    float acc = 0.f;
    for (int j = 0; j < C; j++) acc += m[j] * ts[j];
    zsq = acc * acc;
  }
  __shared__ float sb[4];
  int lane = threadIdx.x & 63, wid = threadIdx.x >> 6;
  for (int off = 32; off; off >>= 1) zsq += __shfl_down(zsq, off, 64);
  if (lane == 0) sb[wid] = zsq;
  __syncthreads();
  if (threadIdx.x == 0) atomicAdd(&ws[WS_OFF_S2 + l], sb[0]+sb[1]+sb[2]+sb[3]);
}

__global__ void wscale_kernel(const float* __restrict__ src, float* __restrict__ dst,
                              int n, const float* __restrict__ tn, const float* __restrict__ s2){
  int i = blockIdx.x * 256 + threadIdx.x;
  if (i >= n) return;
  float inv = sqrtf(tn[0] / s2[0]);   // 1/sigma = ||t|| / ||M t||
  dst[i] = src[i] * inv;
}

// =================== crop/resize bbox ===================
__global__ void bbox_kernel(const float* __restrict__ img, const float* __restrict__ sem,
                            int* __restrict__ bbox){
  int b = blockIdx.x >> 3;
  int s = blockIdx.x & 7;
  int w = threadIdx.x; // 256 threads, one per column
  __shared__ float rowsum[256];
  __shared__ int red[256];
  rowsum[w] = 0.f;
  __syncthreads();
  const float* i0 = img + (size_t)(b*3 + 0) * 65536;
  const float* i1 = i0 + 65536;
  const float* i2 = i1 + 65536;
  const float* mk = sem + (size_t)(b*8 + s) * 65536;
  float colsum = 0.f;
  for (int h = 0; h < 256; h++){
    int off = h*256 + w;
    float v = (i0[off] + i1[off] + i2[off]) * mk[off];
    colsum += v;
    float rv = v;
    for (int o = 32; o; o >>= 1) rv += __shfl_down(rv, o, 64);
    if ((w & 63) == 0) atomicAdd(&rowsum[h], rv);
  }
  __syncthreads();
  // first/last nonzero column (y), row (x)
  red[w] = (colsum != 0.f) ? w : 256; __syncthreads();
  for (int st = 128; st; st >>= 1){ if (w < st) red[w] = min(red[w], red[w+st]); __syncthreads(); }
  int y0 = red[0]; __syncthreads();
  red[w] = (colsum != 0.f) ? w : -1; __syncthreads();
  for (int st = 128; st; st >>= 1){ if (w < st) red[w] = max(red[w], red[w+st]); __syncthreads(); }
  int y1 = red[0]; __syncthreads();
  float rs = rowsum[w];
  red[w] = (rs != 0.f) ? w : 256; __syncthreads();
  for (int st = 128; st; st >>= 1){ if (w < st) red[w] = min(red[w], red[w+st]); __syncthreads(); }
  int x0 = red[0]; __syncthreads();
  red[w] = (rs != 0.f) ? w : -1; __syncthreads();
  for (int st = 128; st; st >>= 1){ if (w < st) red[w] = max(red[w], red[w+st]); __syncthreads(); }
  int x1 = red[0];
  if (w == 0){
    int ok = (y0 < 256) && (x0 < 256);
    int base = blockIdx.x * 4;
    bbox[base+0] = ok ? x0 : 0;
    bbox[base+1] = ok ? (x1 - x0 + 1) : 256;
    bbox[base+2] = ok ? y0 : 0;
    bbox[base+3] = ok ? (y1 - y0 + 1) : 256;
  }
}

__global__ void transimg_kernel(const float* __restrict__ img, const float* __restrict__ sem,
                                const int* __restrict__ bbox, float* __restrict__ out){
  int idx = blockIdx.x * 256 + threadIdx.x;      // total 12,582,912 exactly
  int j = idx & 255;
  int i = (idx >> 8) & 255;
  int c = idx >> 16;           // b*24 + ch24
  int b = c / 24, ch24 = c % 24;
  int s = ch24 / 3, ch = ch24 % 3;
  const int* bb = bbox + (b*8 + s) * 4;
  int ri = bb[0] + ((i * bb[1]) >> 8);
  int cj = bb[2] + ((j * bb[3]) >> 8);
  float m = sem[((size_t)(b*8 + s) * 256 + ri) * 256 + cj];
  float v = img[((size_t)(b*3 + ch) * 256 + ri) * 256 + cj];
  out[idx] = v * m;
}

// =================== grouped 3x3 conv (direct) ===================
__global__ void conv3x3_kernel(const float* __restrict__ in, const float* __restrict__ wt,
                               float* __restrict__ out, int Cin_g, int Cout, int Cout_g,
                               int Hin, int Win, int Hout, int Wout, int stride,
                               int relu_in, int total){
  int idx = blockIdx.x * 256 + threadIdx.x;
  if (idx >= total) return;
  int ow = idx % Wout;
  int t  = idx / Wout;
  int oh = t % Hout; t /= Hout;
  int oc = t % Cout;
  int b  = t / Cout;
  int g = oc / Cout_g;
  int Cin = Cin_g * 8;
  const float* wp = wt + (size_t)oc * Cin_g * 9;
  int ih0 = oh * stride - 1, iw0 = ow * stride - 1;
  float acc = 0.f;
  for (int ic = 0; ic < Cin_g; ic++){
    const float* ip = in + (size_t)(b*Cin + g*Cin_g + ic) * Hin * Win;
    const float* wq = wp + ic * 9;
    #pragma unroll
    for (int kh = 0; kh < 3; kh++){
      int ih = ih0 + kh;
      if ((unsigned)ih >= (unsigned)Hin) continue;
      #pragma unroll
      for (int kw = 0; kw < 3; kw++){
        int iw = iw0 + kw;
        if ((unsigned)iw >= (unsigned)Win) continue;
        float x = ip[ih*Win + iw];
        if (relu_in) x = (x >= 0.f) ? x : 0.2f*x;
        acc += x * wq[kh*3 + kw];
      }
    }
  }
  out[idx] = acc;
}

// =================== instance norm ===================
__global__ void inorm_kernel(const float* __restrict__ in, float* __restrict__ out,
                             int N, int relu_out){
  int bc = blockIdx.x;
  const float* p = in + (size_t)bc * N;
  float* q = out + (size_t)bc * N;
  float s = 0.f, ss = 0.f;
  for (int i = threadIdx.x; i < N; i += blockDim.x){ float x = p[i]; s += x; ss += x*x; }
  __shared__ float sb[8];
  int lane = threadIdx.x & 63, wid = threadIdx.x >> 6;
  for (int o = 32; o; o >>= 1){ s += __shfl_down(s, o, 64); ss += __shfl_down(ss, o, 64); }
  if (lane == 0){ sb[wid] = s; sb[4 + wid] = ss; }
  __syncthreads();
  if (threadIdx.x == 0){
    int nw = blockDim.x >> 6;
    float S = 0.f, SS = 0.f;
    for (int i = 0; i < nw; i++){ S += sb[i]; SS += sb[4+i]; }
    float mean = S / N;
    float var = SS / N - mean*mean;
    sb[0] = mean;
    sb[4] = rsqrtf(var + 1e-5f);
  }
  __syncthreads();
  float mean = sb[0], r = sb[4];
  for (int i = threadIdx.x; i < N; i += blockDim.x){
    float y = (p[i] - mean) * r;
    if (relu_out) y = (y >= 0.f) ? y : 0.2f*y;
    q[i] = y;
  }
}

// =================== 1x1 conv WITH pad-1 output frame ===================
// out shape (B, 2048, Hin+2, Hin+2); border = lrelu(bias); interior (oh-1,ow-1)
__global__ void conv1x1_kernel(const float* __restrict__ in, const float* __restrict__ wt,
                               const float* __restrict__ bias, float* __restrict__ out,
                               int Cin, int Hin, int total){
  int idx = blockIdx.x * 256 + threadIdx.x;
  if (idx >= total) return;
  int Wout = Hin + 2;
  int ow = idx % Wout;
  int t  = idx / Wout;
  int oh = t % Wout; t /= Wout;
  int oc = t % 2048;
  int b  = t / 2048;
  float bv = bias[oc];
  int ih = oh - 1, iw = ow - 1;
  float acc = bv;
  if ((unsigned)ih < (unsigned)Hin && (unsigned)iw < (unsigned)Hin){
    int HW = Hin * Hin;
    const float* ip = in + (size_t)b * Cin * HW + ih * Hin + iw;
    const float* wp = wt + (size_t)oc * Cin;
    for (int ic = 0; ic < Cin; ic++){
      float x = ip[(size_t)ic * HW];
      x = (x >= 0.f) ? x : 0.2f*x;
      acc += x * wp[ic];
    }
  }
  out[idx] = (acc >= 0.f) ? acc : 0.2f*acc;
}

// =================== host ===================
extern "C" void kernel_launch(void* const* d_in, const int* in_sizes, int n_in,
                              void* d_out, int out_size, void* d_ws, size_t ws_size,
                              hipStream_t stream){
  const float* img = (const float*)d_in[0];
  const float* sem = (const float*)d_in[1];
  Ptr6 wp;
  for (int l = 0; l < 6; l++) wp.p[l] = (const float*)d_in[2 + l];
  const float* gw1 = (const float*)d_in[8];
  const float* gb1 = (const float*)d_in[9];
  const float* gw2 = (const float*)d_in[10];
  const float* gb2 = (const float*)d_in[11];
  float* out = (float*)d_out;
  float* ws  = (float*)d_ws;

  float* bufA = out + OUT_X2;            // 8,388,608 floats scratch (inside x_2 region)
  float* bufB = bufA + 8388608;          // 8,388,608 floats scratch
  float* bufC = ws + WS_OFF_C;           // out_8 norm
  float* bufD = ws + WS_OFF_D;           // out_16 norm
  int* bbox = (int*)(ws + WS_OFF_BBOX);

  static const int kWOff[6]  = {0,1728,10944,47808,195264,785088};
  static const int kWSize[6] = {1728,9216,36864,147456,589824,2359296};

  // zero t / tn / s2 (atomic accumulators) — ws is poisoned each call
  hipMemsetAsync(ws + WS_OFF_T, 0, (WS_OFF_S2 + 8 - WS_OFF_T) * sizeof(float), stream);

  gen_u_kernel<<<1, 64, 0, stream>>>(ws);
  sn_t_kernel<<<32, 256, 0, stream>>>(wp, ws);
  sn_tn_kernel<<<6, 256, 0, stream>>>(ws);
  sn_sig_kernel<<<17, 256, 0, stream>>>(wp, ws);
  for (int l = 0; l < 6; l++)
    wscale_kernel<<<(kWSize[l]+255)/256, 256, 0, stream>>>(wp.p[l], ws + WS_OFF_W + kWOff[l],
                                                           kWSize[l], ws + WS_OFF_TN + l, ws + WS_OFF_S2 + l);

  bbox_kernel<<<64, 256, 0, stream>>>(img, sem, bbox);
  transimg_kernel<<<49152, 256, 0, stream>>>(img, sem, bbox, out + OUT_IMG);

  // conv1: images(8,24,256,256) -> (8,64,128,128)
  conv3x3_kernel<<<32768, 256, 0, stream>>>(out + OUT_IMG, ws + WS_OFF_W + kWOff[0], bufA,
                                            3, 64, 8, 256,256, 128,128, 2, 0, 8388608);
  inorm_kernel<<<512, 256, 0, stream>>>(bufA, bufB, 16384, 0);
  // conv2 -> (8,128,64,64)
  conv3x3_kernel<<<16384, 256, 0, stream>>>(bufB, ws + WS_OFF_W + kWOff[1], bufA,
                                            8, 128, 16, 128,128, 64,64, 2, 1, 4194304);
  inorm_kernel<<<1024, 256, 0, stream>>>(bufA, bufB, 4096, 0);
  // conv3 -> out_8 (8,256,32,32)
  conv3x3_kernel<<<8192, 256, 0, stream>>>(bufB, ws + WS_OFF_W + kWOff[2], bufA,
                                           16, 256, 32, 64,64, 32,32, 2, 1, 2097152);
  inorm_kernel<<<2048, 256, 0, stream>>>(bufA, bufC, 1024, 0);
  // conv4 -> out_16 (8,512,16,16)
  conv3x3_kernel<<<4096, 256, 0, stream>>>(bufC, ws + WS_OFF_W + kWOff[3], bufA,
                                           32, 512, 64, 32,32, 16,16, 2, 1, 1048576);
  inorm_kernel<<<4096, 256, 0, stream>>>(bufA, bufD, 256, 0);
  // conv5 -> out_32 (8,1024,8,8)
  conv3x3_kernel<<<2048, 256, 0, stream>>>(bufD, ws + WS_OFF_W + kWOff[4], bufA,
                                           64, 1024, 128, 16,16, 8,8, 2, 1, 524288);
  inorm_kernel<<<8192, 64, 0, stream>>>(bufA, bufB, 64, 0);
  // conv6 -> (8,2048,8,8), stride 1
  conv3x3_kernel<<<4096, 256, 0, stream>>>(bufB, ws + WS_OFF_W + kWOff[5], bufA,
                                           128, 2048, 256, 8,8, 8,8, 1, 1, 1048576);
  inorm_kernel<<<16384, 64, 0, stream>>>(bufA, out + OUT_X, 64, 1);   // x (lrelu on output)

  // x_1 = lrelu(conv1x1(lrelu(out_16), gw1) + gb1), out (8,2048,18,18)
  conv1x1_kernel<<<20736, 256, 0, stream>>>(bufD, gw1, gb1, out + OUT_X1, 512, 16, 5308416);
  // x_2 = lrelu(conv1x1(lrelu(out_8), gw2) + gb2), out (8,2048,34,34)  (overwrites bufA/bufB)
  conv1x1_kernel<<<73984, 256, 0, stream>>>(bufC, gw2, gb2, out + OUT_X2, 256, 32, 18939904);
}

// Round 3
// 2331.834 us; speedup vs baseline: 2.8962x; 2.8962x over previous
//
#include <hip/hip_runtime.h>
#include <math.h>

// ---------------- workspace layout (float indices) ----------------
#define WS_OFF_U     0        // 4032 used, pad to 4096
#define WS_OFF_T     4096     // 2304 (t vectors, zeroed)
#define WS_OFF_TN    6400     // 6 (+2 pad)  ||t||^2 per layer (zeroed)
#define WS_OFF_S2    6408     // 6 (+2 pad)  ||M t||^2 per layer (zeroed)
#define WS_OFF_BBOX  6416     // 256 ints (64 tuples x {x0,h,y0,w})
#define WS_OFF_W     8192     // 3,144,384 scaled weights
#define WS_OFF_C     3152896  // 2,097,152 out_8 normalized
#define WS_OFF_D     5250048  // 1,048,576 out_16 normalized

// ---------------- d_out layout (float offsets) ----------------
// The 1x1 convs in the reference ALSO get padding (1,1) -> 18x18 / 34x34.
#define OUT_X    0          // 8*2048*8*8     = 1,048,576
#define OUT_X1   1048576    // 8*2048*18*18   = 5,308,416
#define OUT_X2   6356992    // 8*2048*34*34   = 18,939,904 (also hosts bufA/bufB scratch)
#define OUT_IMG  25296896   // 8*24*256*256   = 12,582,912

struct Ptr6 { const float* p[6]; };

// =================== parallel MT19937 + Marsaglia polar (numpy RandomState) ===================
// One block per layer. State in LDS; twist parallelized in 4 dependency phases;
// polar attempts evaluated in parallel (4 uint32s each, fixed stream positions);
// accepted-attempt -> output-pair mapping via block prefix sum.
#define MT_UP 0x80000000u
#define MT_LO 0x7fffffffu

__global__ __launch_bounds__(256) void gen_u_par(float* ws){
  const int os[6]   = {64,128,256,512,1024,2048};
  const int uoff[6] = {0,64,192,448,960,1984};
  int l = blockIdx.x;
  int n = os[l];
  int tid = threadIdx.x;

  __shared__ unsigned mt[624];
  __shared__ unsigned draws[8192];
  __shared__ float px[2048], py[2048];
  __shared__ unsigned char accf[2048];
  __shared__ int scan[256];

  if (tid == 0){
    unsigned seed = (unsigned)(l + 1);
    for (int i = 0; i < 624; i++){
      mt[i] = seed;
      seed = 1812433253u * (seed ^ (seed >> 30)) + (unsigned)(i + 1);
    }
  }
  __syncthreads();

  int need = 4 * n;                 // uint32 draws needed (<= 8192)
  int twists = (need + 623) / 624;
  for (int t = 0; t < twists; t++){
    // phase A: i in [0,227)  (all inputs old)
    unsigned yA = 0, vA = 0;
    if (tid < 227){ yA = (mt[tid] & MT_UP) | (mt[tid+1] & MT_LO); vA = mt[tid+397]; }
    __syncthreads();
    if (tid < 227){ mt[tid] = vA ^ (yA >> 1) ^ ((yA & 1u) ? 0x9908b0dfu : 0u); }
    __syncthreads();
    // phase B1: i in [227,454)   (mt[i-227] is new from A)
    unsigned yB = 0, vB = 0; int iB = 227 + tid;
    if (tid < 227){ yB = (mt[iB] & MT_UP) | (mt[iB+1] & MT_LO); vB = mt[iB-227]; }
    __syncthreads();
    if (tid < 227){ mt[iB] = vB ^ (yB >> 1) ^ ((yB & 1u) ? 0x9908b0dfu : 0u); }
    __syncthreads();
    // phase B2: i in [454,623)   (mt[i-227] is new from B1)
    unsigned yC = 0, vC = 0; int iC = 454 + tid;
    if (tid < 169){ yC = (mt[iC] & MT_UP) | (mt[iC+1] & MT_LO); vC = mt[iC-227]; }
    __syncthreads();
    if (tid < 169){ mt[iC] = vC ^ (yC >> 1) ^ ((yC & 1u) ? 0x9908b0dfu : 0u); }
    __syncthreads();
    // phase C: i = 623 (uses new mt[0], new mt[396])
    if (tid == 0){
      unsigned y = (mt[623] & MT_UP) | (mt[0] & MT_LO);
      mt[623] = mt[396] ^ (y >> 1) ^ ((y & 1u) ? 0x9908b0dfu : 0u);
    }
    __syncthreads();
    // temper -> draws
    for (int i = tid; i < 624; i += 256){
      int pos = t * 624 + i;
      if (pos < need){
        unsigned y = mt[i];
        y ^= y >> 11; y ^= (y << 7) & 0x9d2c5680u; y ^= (y << 15) & 0xefc60000u; y ^= y >> 18;
        draws[pos] = y;
      }
    }
    __syncthreads();
  }

  // polar attempts: attempt k consumes draws[4k..4k+3]
  int A = (n + 255) / 256;
  int local = 0;
  for (int a = 0; a < A; a++){
    int k = tid * A + a;
    if (k < n){
      double u1 = ((draws[4*k]   >> 5) * 67108864.0 + (draws[4*k+1] >> 6)) / 9007199254740992.0;
      double u2 = ((draws[4*k+2] >> 5) * 67108864.0 + (draws[4*k+3] >> 6)) / 9007199254740992.0;
      double x1 = 2.0*u1 - 1.0, x2 = 2.0*u2 - 1.0;
      double r2 = x1*x1 + x2*x2;
      int ok = (r2 < 1.0 && r2 != 0.0);
      accf[k] = (unsigned char)ok;
      if (ok){
        double f = sqrt(-2.0 * log(r2) / r2);
        px[k] = (float)(f * x2);   // delivered first
        py[k] = (float)(f * x1);   // cached, delivered second
      }
      local += ok;
    }
  }
  scan[tid] = local;
  __syncthreads();
  if (tid == 0){
    int run = 0;
    for (int i = 0; i < 256; i++){ int c = scan[i]; scan[i] = run; run += c; }
  }
  __syncthreads();
  int j = scan[tid];
  float* u = ws + WS_OFF_U + uoff[l];
  for (int a = 0; a < A; a++){
    int k = tid * A + a;
    if (k < n && accf[k]){
      if (2*j + 1 < n){ u[2*j] = px[k]; u[2*j+1] = py[k]; }
      j++;
    }
  }
}

// =================== spectral norm: t = M^T u (atomic partial) ===================
__global__ void sn_t_kernel(Ptr6 wp, float* ws){
  const int o[6]    = {64,128,256,512,1024,2048};
  const int cols[6] = {27,72,144,288,576,1152};
  const int uoff[6] = {0,64,192,448,960,1984};
  const int toff[6] = {0,27,99,243,531,1107};
  const int bstart[7] = {0,1,2,4,8,16,32};
  int b = blockIdx.x;
  int l = 0; while (l < 5 && b >= bstart[l+1]) l++;
  int chunk = b - bstart[l];
  int r0 = chunk * 128;
  int r1 = min(r0 + 128, o[l]);
  const float* m = wp.p[l];
  const float* u = ws + WS_OFF_U + uoff[l];
  float* t = ws + WS_OFF_T + toff[l];
  int C = cols[l];
  for (int j = threadIdx.x; j < C; j += blockDim.x){
    float acc = 0.f;
    for (int r = r0; r < r1; r++) acc += m[(size_t)r * C + j] * u[r];
    atomicAdd(&t[j], acc);
  }
}

__global__ void sn_tn_kernel(float* ws){
  const int cols[6] = {27,72,144,288,576,1152};
  const int toff[6] = {0,27,99,243,531,1107};
  int l = blockIdx.x;
  const float* t = ws + WS_OFF_T + toff[l];
  float s = 0.f;
  for (int j = threadIdx.x; j < cols[l]; j += 256){ float v = t[j]; s += v*v; }
  __shared__ float sb[4];
  int lane = threadIdx.x & 63, wid = threadIdx.x >> 6;
  for (int o = 32; o; o >>= 1) s += __shfl_down(s, o, 64);
  if (lane == 0) sb[wid] = s;
  __syncthreads();
  if (threadIdx.x == 0) ws[WS_OFF_TN + l] = sb[0] + sb[1] + sb[2] + sb[3];
}

__global__ void sn_sig_kernel(Ptr6 wp, float* ws){
  const int o[6]    = {64,128,256,512,1024,2048};
  const int cols[6] = {27,72,144,288,576,1152};
  const int toff[6] = {0,27,99,243,531,1107};
  const int bstart[7] = {0,1,2,3,5,9,17};
  int b = blockIdx.x;
  int l = 0; while (l < 5 && b >= bstart[l+1]) l++;
  int chunk = b - bstart[l];
  int r0 = chunk * 256;
  int r1 = min(r0 + 256, o[l]);
  int C = cols[l];
  __shared__ float ts[1152];
  const float* t = ws + WS_OFF_T + toff[l];
  for (int j = threadIdx.x; j < C; j += 256) ts[j] = t[j];
  __syncthreads();
  float zsq = 0.f;
  int r = r0 + (int)threadIdx.x;
  if (r < r1){
    const float* m = wp.p[l] + (size_t)r * C;
    float acc = 0.f;
    for (int j = 0; j < C; j++) acc += m[j] * ts[j];
    zsq = acc * acc;
  }
  __shared__ float sb[4];
  int lane = threadIdx.x & 63, wid = threadIdx.x >> 6;
  for (int off = 32; off; off >>= 1) zsq += __shfl_down(zsq, off, 64);
  if (lane == 0) sb[wid] = zsq;
  __syncthreads();
  if (threadIdx.x == 0) atomicAdd(&ws[WS_OFF_S2 + l], sb[0]+sb[1]+sb[2]+sb[3]);
}

__global__ void wscale_kernel(const float* __restrict__ src, float* __restrict__ dst,
                              int n, const float* __restrict__ tn, const float* __restrict__ s2){
  int i = blockIdx.x * 256 + threadIdx.x;
  if (i >= n) return;
  float inv = sqrtf(tn[0] / s2[0]);   // 1/sigma = ||t|| / ||M t||
  dst[i] = src[i] * inv;
}

// =================== crop/resize bbox ===================
__global__ void bbox_kernel(const float* __restrict__ img, const float* __restrict__ sem,
                            int* __restrict__ bbox){
  int b = blockIdx.x >> 3;
  int s = blockIdx.x & 7;
  int w = threadIdx.x; // 256 threads, one per column
  __shared__ float rowsum[256];
  __shared__ int red[256];
  rowsum[w] = 0.f;
  __syncthreads();
  const float* i0 = img + (size_t)(b*3 + 0) * 65536;
  const float* i1 = i0 + 65536;
  const float* i2 = i1 + 65536;
  const float* mk = sem + (size_t)(b*8 + s) * 65536;
  float colsum = 0.f;
  for (int h = 0; h < 256; h++){
    int off = h*256 + w;
    float v = (i0[off] + i1[off] + i2[off]) * mk[off];
    colsum += v;
    float rv = v;
    for (int o = 32; o; o >>= 1) rv += __shfl_down(rv, o, 64);
    if ((w & 63) == 0) atomicAdd(&rowsum[h], rv);
  }
  __syncthreads();
  red[w] = (colsum != 0.f) ? w : 256; __syncthreads();
  for (int st = 128; st; st >>= 1){ if (w < st) red[w] = min(red[w], red[w+st]); __syncthreads(); }
  int y0 = red[0]; __syncthreads();
  red[w] = (colsum != 0.f) ? w : -1; __syncthreads();
  for (int st = 128; st; st >>= 1){ if (w < st) red[w] = max(red[w], red[w+st]); __syncthreads(); }
  int y1 = red[0]; __syncthreads();
  float rs = rowsum[w];
  red[w] = (rs != 0.f) ? w : 256; __syncthreads();
  for (int st = 128; st; st >>= 1){ if (w < st) red[w] = min(red[w], red[w+st]); __syncthreads(); }
  int x0 = red[0]; __syncthreads();
  red[w] = (rs != 0.f) ? w : -1; __syncthreads();
  for (int st = 128; st; st >>= 1){ if (w < st) red[w] = max(red[w], red[w+st]); __syncthreads(); }
  int x1 = red[0];
  if (w == 0){
    int ok = (y0 < 256) && (x0 < 256);
    int base = blockIdx.x * 4;
    bbox[base+0] = ok ? x0 : 0;
    bbox[base+1] = ok ? (x1 - x0 + 1) : 256;
    bbox[base+2] = ok ? y0 : 0;
    bbox[base+3] = ok ? (y1 - y0 + 1) : 256;
  }
}

__global__ void transimg_kernel(const float* __restrict__ img, const float* __restrict__ sem,
                                const int* __restrict__ bbox, float* __restrict__ out){
  int idx = blockIdx.x * 256 + threadIdx.x;      // total 12,582,912 exactly
  int j = idx & 255;
  int i = (idx >> 8) & 255;
  int c = idx >> 16;           // b*24 + ch24
  int b = c / 24, ch24 = c % 24;
  int s = ch24 / 3, ch = ch24 % 3;
  const int* bb = bbox + (b*8 + s) * 4;
  int ri = bb[0] + ((i * bb[1]) >> 8);
  int cj = bb[2] + ((j * bb[3]) >> 8);
  float m = sem[((size_t)(b*8 + s) * 256 + ri) * 256 + cj];
  float v = img[((size_t)(b*3 + ch) * 256 + ri) * 256 + cj];
  out[idx] = v * m;
}

// =================== grouped 3x3 conv (direct) ===================
__global__ void conv3x3_kernel(const float* __restrict__ in, const float* __restrict__ wt,
                               float* __restrict__ out, int Cin_g, int Cout, int Cout_g,
                               int Hin, int Win, int Hout, int Wout, int stride,
                               int relu_in, int total){
  int idx = blockIdx.x * 256 + threadIdx.x;
  if (idx >= total) return;
  int ow = idx % Wout;
  int t  = idx / Wout;
  int oh = t % Hout; t /= Hout;
  int oc = t % Cout;
  int b  = t / Cout;
  int g = oc / Cout_g;
  int Cin = Cin_g * 8;
  const float* wp = wt + (size_t)oc * Cin_g * 9;
  int ih0 = oh * stride - 1, iw0 = ow * stride - 1;
  float acc = 0.f;
  for (int ic = 0; ic < Cin_g; ic++){
    const float* ip = in + (size_t)(b*Cin + g*Cin_g + ic) * Hin * Win;
    const float* wq = wp + ic * 9;
    #pragma unroll
    for (int kh = 0; kh < 3; kh++){
      int ih = ih0 + kh;
      if ((unsigned)ih >= (unsigned)Hin) continue;
      #pragma unroll
      for (int kw = 0; kw < 3; kw++){
        int iw = iw0 + kw;
        if ((unsigned)iw >= (unsigned)Win) continue;
        float x = ip[ih*Win + iw];
        if (relu_in) x = (x >= 0.f) ? x : 0.2f*x;
        acc += x * wq[kh*3 + kw];
      }
    }
  }
  out[idx] = acc;
}

// =================== instance norm ===================
__global__ void inorm_kernel(const float* __restrict__ in, float* __restrict__ out,
                             int N, int relu_out){
  int bc = blockIdx.x;
  const float* p = in + (size_t)bc * N;
  float* q = out + (size_t)bc * N;
  float s = 0.f, ss = 0.f;
  for (int i = threadIdx.x; i < N; i += blockDim.x){ float x = p[i]; s += x; ss += x*x; }
  __shared__ float sb[8];
  int lane = threadIdx.x & 63, wid = threadIdx.x >> 6;
  for (int o = 32; o; o >>= 1){ s += __shfl_down(s, o, 64); ss += __shfl_down(ss, o, 64); }
  if (lane == 0){ sb[wid] = s; sb[4 + wid] = ss; }
  __syncthreads();
  if (threadIdx.x == 0){
    int nw = blockDim.x >> 6;
    float S = 0.f, SS = 0.f;
    for (int i = 0; i < nw; i++){ S += sb[i]; SS += sb[4+i]; }
    float mean = S / N;
    float var = SS / N - mean*mean;
    sb[0] = mean;
    sb[4] = rsqrtf(var + 1e-5f);
  }
  __syncthreads();
  float mean = sb[0], r = sb[4];
  for (int i = threadIdx.x; i < N; i += blockDim.x){
    float y = (p[i] - mean) * r;
    if (relu_out) y = (y >= 0.f) ? y : 0.2f*y;
    q[i] = y;
  }
}

// =================== 1x1 conv as tiled GEMM (interior of padded output) ===================
// in: (8, Cin, H, H) pre-activation (lrelu applied on load); wt: (2048, Cin); bias: (2048)
// out: (8, 2048, H+2, H+2), interior only. 64 oc x 64 pix per block, 4x4 per thread.
__global__ __launch_bounds__(256) void conv1x1_gemm(const float* __restrict__ in,
                                                    const float* __restrict__ wt,
                                                    const float* __restrict__ bias,
                                                    float* __restrict__ out,
                                                    int Cin, int H){
  int HW = H * H;
  int b   = blockIdx.z;
  int oc0 = blockIdx.y * 64;
  int pix0 = blockIdx.x * 64;
  __shared__ float Ws[16][68];   // [k][oc]  pad->2-way max, float4-aligned rows
  __shared__ float Xs[16][68];   // [k][pix]
  int tid = threadIdx.x;
  int tx = tid & 15, ty = tid >> 4;
  float acc[4][4];
  #pragma unroll
  for (int i = 0; i < 4; i++)
    #pragma unroll
    for (int j = 0; j < 4; j++) acc[i][j] = 0.f;

  for (int k0 = 0; k0 < Cin; k0 += 16){
    #pragma unroll
    for (int r = 0; r < 4; r++){
      int oc_l = (tid >> 4) + 16*r;
      int kk = tid & 15;
      Ws[kk][oc_l] = wt[(size_t)(oc0 + oc_l) * Cin + k0 + kk];
    }
    {
      int pixl = tid & 63;
      int kkb = (tid >> 6) << 2;
      #pragma unroll
      for (int r = 0; r < 4; r++){
        int kk = kkb + r;
        float x = in[(size_t)(b * Cin + k0 + kk) * HW + pix0 + pixl];
        Xs[kk][pixl] = (x >= 0.f) ? x : 0.2f*x;
      }
    }
    __syncthreads();
    #pragma unroll
    for (int kk = 0; kk < 16; kk++){
      float4 wv = *(const float4*)&Ws[kk][ty*4];
      float4 xv = *(const float4*)&Xs[kk][tx*4];
      acc[0][0] += wv.x*xv.x; acc[0][1] += wv.x*xv.y; acc[0][2] += wv.x*xv.z; acc[0][3] += wv.x*xv.w;
      acc[1][0] += wv.y*xv.x; acc[1][1] += wv.y*xv.y; acc[1][2] += wv.y*xv.z; acc[1][3] += wv.y*xv.w;
      acc[2][0] += wv.z*xv.x; acc[2][1] += wv.z*xv.y; acc[2][2] += wv.z*xv.z; acc[2][3] += wv.z*xv.w;
      acc[3][0] += wv.w*xv.x; acc[3][1] += wv.w*xv.y; acc[3][2] += wv.w*xv.z; acc[3][3] += wv.w*xv.w;
    }
    __syncthreads();
  }

  int Wp = H + 2;
  #pragma unroll
  for (int i = 0; i < 4; i++){
    int oc = oc0 + ty*4 + i;
    float bv = bias[oc];
    #pragma unroll
    for (int j = 0; j < 4; j++){
      int pix = pix0 + tx*4 + j;
      int ph = pix / H, pw = pix % H;
      float v = acc[i][j] + bv;
      v = (v >= 0.f) ? v : 0.2f*v;
      out[(((size_t)b*2048 + oc)*Wp + ph + 1)*Wp + pw + 1] = v;
    }
  }
}

// border of padded 1x1-conv output = lrelu(bias)
__global__ void fill_border_kernel(const float* __restrict__ bias, float* __restrict__ out,
                                   int H, int total){
  int idx = blockIdx.x * 256 + threadIdx.x;
  if (idx >= total) return;
  int Wp = H + 2;
  int pw = idx % Wp; int t = idx / Wp;
  int ph = t % Wp;   t /= Wp;
  int oc = t % 2048;
  if (ph != 0 && ph != Wp-1 && pw != 0 && pw != Wp-1) return;
  float bv = bias[oc];
  out[idx] = (bv >= 0.f) ? bv : 0.2f*bv;
}

// =================== host ===================
extern "C" void kernel_launch(void* const* d_in, const int* in_sizes, int n_in,
                              void* d_out, int out_size, void* d_ws, size_t ws_size,
                              hipStream_t stream){
  const float* img = (const float*)d_in[0];
  const float* sem = (const float*)d_in[1];
  Ptr6 wp;
  for (int l = 0; l < 6; l++) wp.p[l] = (const float*)d_in[2 + l];
  const float* gw1 = (const float*)d_in[8];
  const float* gb1 = (const float*)d_in[9];
  const float* gw2 = (const float*)d_in[10];
  const float* gb2 = (const float*)d_in[11];
  float* out = (float*)d_out;
  float* ws  = (float*)d_ws;

  float* bufA = out + OUT_X2;            // scratch inside x_2 region (written last)
  float* bufB = bufA + 8388608;
  float* bufC = ws + WS_OFF_C;           // out_8 normalized
  float* bufD = ws + WS_OFF_D;           // out_16 normalized
  int* bbox = (int*)(ws + WS_OFF_BBOX);

  static const int kWOff[6]  = {0,1728,10944,47808,195264,785088};
  static const int kWSize[6] = {1728,9216,36864,147456,589824,2359296};

  hipMemsetAsync(ws + WS_OFF_T, 0, (WS_OFF_S2 + 8 - WS_OFF_T) * sizeof(float), stream);

  gen_u_par<<<6, 256, 0, stream>>>(ws);
  sn_t_kernel<<<32, 256, 0, stream>>>(wp, ws);
  sn_tn_kernel<<<6, 256, 0, stream>>>(ws);
  sn_sig_kernel<<<17, 256, 0, stream>>>(wp, ws);
  for (int l = 0; l < 6; l++)
    wscale_kernel<<<(kWSize[l]+255)/256, 256, 0, stream>>>(wp.p[l], ws + WS_OFF_W + kWOff[l],
                                                           kWSize[l], ws + WS_OFF_TN + l, ws + WS_OFF_S2 + l);

  bbox_kernel<<<64, 256, 0, stream>>>(img, sem, bbox);
  transimg_kernel<<<49152, 256, 0, stream>>>(img, sem, bbox, out + OUT_IMG);

  // conv1: images(8,24,256,256) -> (8,64,128,128)
  conv3x3_kernel<<<32768, 256, 0, stream>>>(out + OUT_IMG, ws + WS_OFF_W + kWOff[0], bufA,
                                            3, 64, 8, 256,256, 128,128, 2, 0, 8388608);
  inorm_kernel<<<512, 256, 0, stream>>>(bufA, bufB, 16384, 0);
  // conv2 -> (8,128,64,64)
  conv3x3_kernel<<<16384, 256, 0, stream>>>(bufB, ws + WS_OFF_W + kWOff[1], bufA,
                                            8, 128, 16, 128,128, 64,64, 2, 1, 4194304);
  inorm_kernel<<<1024, 256, 0, stream>>>(bufA, bufB, 4096, 0);
  // conv3 -> out_8 (8,256,32,32)
  conv3x3_kernel<<<8192, 256, 0, stream>>>(bufB, ws + WS_OFF_W + kWOff[2], bufA,
                                           16, 256, 32, 64,64, 32,32, 2, 1, 2097152);
  inorm_kernel<<<2048, 256, 0, stream>>>(bufA, bufC, 1024, 0);
  // conv4 -> out_16 (8,512,16,16)
  conv3x3_kernel<<<4096, 256, 0, stream>>>(bufC, ws + WS_OFF_W + kWOff[3], bufA,
                                           32, 512, 64, 32,32, 16,16, 2, 1, 1048576);
  inorm_kernel<<<4096, 256, 0, stream>>>(bufA, bufD, 256, 0);
  // conv5 -> out_32 (8,1024,8,8)
  conv3x3_kernel<<<2048, 256, 0, stream>>>(bufD, ws + WS_OFF_W + kWOff[4], bufA,
                                           64, 1024, 128, 16,16, 8,8, 2, 1, 524288);
  inorm_kernel<<<8192, 64, 0, stream>>>(bufA, bufB, 64, 0);
  // conv6 -> (8,2048,8,8), stride 1
  conv3x3_kernel<<<4096, 256, 0, stream>>>(bufB, ws + WS_OFF_W + kWOff[5], bufA,
                                           128, 2048, 256, 8,8, 8,8, 1, 1, 1048576);
  inorm_kernel<<<16384, 64, 0, stream>>>(bufA, out + OUT_X, 64, 1);   // x

  // x_1 = lrelu(conv1x1(lrelu(out_16), gw1) + gb1) -> (8,2048,18,18)
  fill_border_kernel<<<(5308416+255)/256, 256, 0, stream>>>(gb1, out + OUT_X1, 16, 5308416);
  conv1x1_gemm<<<dim3(4, 32, 8), 256, 0, stream>>>(bufD, gw1, gb1, out + OUT_X1, 512, 16);
  // x_2 = lrelu(conv1x1(lrelu(out_8), gw2) + gb2) -> (8,2048,34,34)
  fill_border_kernel<<<(18939904+255)/256, 256, 0, stream>>>(gb2, out + OUT_X2, 32, 18939904);
  conv1x1_gemm<<<dim3(16, 32, 8), 256, 0, stream>>>(bufC, gw2, gb2, out + OUT_X2, 256, 32);
}

// Round 4
// 1433.979 us; speedup vs baseline: 4.7096x; 1.6261x over previous
//
#include <hip/hip_runtime.h>
#include <math.h>

// ---------------- workspace layout (float indices) ----------------
#define WS_OFF_U     0
#define WS_OFF_T     4096
#define WS_OFF_TN    6400
#define WS_OFF_S2    6408
#define WS_OFF_BBOX  6416
#define WS_OFF_W     8192
#define WS_OFF_C     3152896  // out_8 normalized (2,097,152)
#define WS_OFF_D     5250048  // out_16 normalized (1,048,576)

// ---------------- d_out layout (float offsets) ----------------
#define OUT_X    0          // 8*2048*8*8     = 1,048,576
#define OUT_X1   1048576    // 8*2048*18*18   = 5,308,416
#define OUT_X2   6356992    // 8*2048*34*34   = 18,939,904 (hosts bufA/bufB scratch)
#define OUT_IMG  25296896   // 8*24*256*256   = 12,582,912

struct Ptr6 { const float* p[6]; };

// =================== parallel MT19937 + Marsaglia polar (numpy RandomState) ===================
#define MT_UP 0x80000000u
#define MT_LO 0x7fffffffu

__global__ __launch_bounds__(256) void gen_u_par(float* ws){
  const int os[6]   = {64,128,256,512,1024,2048};
  const int uoff[6] = {0,64,192,448,960,1984};
  int l = blockIdx.x;
  int n = os[l];
  int tid = threadIdx.x;

  __shared__ unsigned mt[624];
  __shared__ unsigned draws[8192];
  __shared__ float px[2048], py[2048];
  __shared__ unsigned char accf[2048];
  __shared__ int scan[256];

  if (tid == 0){
    unsigned seed = (unsigned)(l + 1);
    for (int i = 0; i < 624; i++){
      mt[i] = seed;
      seed = 1812433253u * (seed ^ (seed >> 30)) + (unsigned)(i + 1);
    }
  }
  __syncthreads();

  int need = 4 * n;
  int twists = (need + 623) / 624;
  for (int t = 0; t < twists; t++){
    unsigned yA = 0, vA = 0;
    if (tid < 227){ yA = (mt[tid] & MT_UP) | (mt[tid+1] & MT_LO); vA = mt[tid+397]; }
    __syncthreads();
    if (tid < 227){ mt[tid] = vA ^ (yA >> 1) ^ ((yA & 1u) ? 0x9908b0dfu : 0u); }
    __syncthreads();
    unsigned yB = 0, vB = 0; int iB = 227 + tid;
    if (tid < 227){ yB = (mt[iB] & MT_UP) | (mt[iB+1] & MT_LO); vB = mt[iB-227]; }
    __syncthreads();
    if (tid < 227){ mt[iB] = vB ^ (yB >> 1) ^ ((yB & 1u) ? 0x9908b0dfu : 0u); }
    __syncthreads();
    unsigned yC = 0, vC = 0; int iC = 454 + tid;
    if (tid < 169){ yC = (mt[iC] & MT_UP) | (mt[iC+1] & MT_LO); vC = mt[iC-227]; }
    __syncthreads();
    if (tid < 169){ mt[iC] = vC ^ (yC >> 1) ^ ((yC & 1u) ? 0x9908b0dfu : 0u); }
    __syncthreads();
    if (tid == 0){
      unsigned y = (mt[623] & MT_UP) | (mt[0] & MT_LO);
      mt[623] = mt[396] ^ (y >> 1) ^ ((y & 1u) ? 0x9908b0dfu : 0u);
    }
    __syncthreads();
    for (int i = tid; i < 624; i += 256){
      int pos = t * 624 + i;
      if (pos < need){
        unsigned y = mt[i];
        y ^= y >> 11; y ^= (y << 7) & 0x9d2c5680u; y ^= (y << 15) & 0xefc60000u; y ^= y >> 18;
        draws[pos] = y;
      }
    }
    __syncthreads();
  }

  int A = (n + 255) / 256;
  int local = 0;
  for (int a = 0; a < A; a++){
    int k = tid * A + a;
    if (k < n){
      double u1 = ((draws[4*k]   >> 5) * 67108864.0 + (draws[4*k+1] >> 6)) / 9007199254740992.0;
      double u2 = ((draws[4*k+2] >> 5) * 67108864.0 + (draws[4*k+3] >> 6)) / 9007199254740992.0;
      double x1 = 2.0*u1 - 1.0, x2 = 2.0*u2 - 1.0;
      double r2 = x1*x1 + x2*x2;
      int ok = (r2 < 1.0 && r2 != 0.0);
      accf[k] = (unsigned char)ok;
      if (ok){
        double f = sqrt(-2.0 * log(r2) / r2);
        px[k] = (float)(f * x2);
        py[k] = (float)(f * x1);
      }
      local += ok;
    }
  }
  scan[tid] = local;
  __syncthreads();
  if (tid == 0){
    int run = 0;
    for (int i = 0; i < 256; i++){ int c = scan[i]; scan[i] = run; run += c; }
  }
  __syncthreads();
  int j = scan[tid];
  float* u = ws + WS_OFF_U + uoff[l];
  for (int a = 0; a < A; a++){
    int k = tid * A + a;
    if (k < n && accf[k]){
      if (2*j + 1 < n){ u[2*j] = px[k]; u[2*j+1] = py[k]; }
      j++;
    }
  }
}

// =================== spectral norm ===================
__global__ void sn_t_kernel(Ptr6 wp, float* ws){
  const int o[6]    = {64,128,256,512,1024,2048};
  const int cols[6] = {27,72,144,288,576,1152};
  const int uoff[6] = {0,64,192,448,960,1984};
  const int toff[6] = {0,27,99,243,531,1107};
  const int bstart[7] = {0,1,2,4,8,16,32};
  int b = blockIdx.x;
  int l = 0; while (l < 5 && b >= bstart[l+1]) l++;
  int chunk = b - bstart[l];
  int r0 = chunk * 128;
  int r1 = min(r0 + 128, o[l]);
  const float* m = wp.p[l];
  const float* u = ws + WS_OFF_U + uoff[l];
  float* t = ws + WS_OFF_T + toff[l];
  int C = cols[l];
  for (int j = threadIdx.x; j < C; j += blockDim.x){
    float acc = 0.f;
    for (int r = r0; r < r1; r++) acc += m[(size_t)r * C + j] * u[r];
    atomicAdd(&t[j], acc);
  }
}

__global__ void sn_tn_kernel(float* ws){
  const int cols[6] = {27,72,144,288,576,1152};
  const int toff[6] = {0,27,99,243,531,1107};
  int l = blockIdx.x;
  const float* t = ws + WS_OFF_T + toff[l];
  float s = 0.f;
  for (int j = threadIdx.x; j < cols[l]; j += 256){ float v = t[j]; s += v*v; }
  __shared__ float sb[4];
  int lane = threadIdx.x & 63, wid = threadIdx.x >> 6;
  for (int o = 32; o; o >>= 1) s += __shfl_down(s, o, 64);
  if (lane == 0) sb[wid] = s;
  __syncthreads();
  if (threadIdx.x == 0) ws[WS_OFF_TN + l] = sb[0] + sb[1] + sb[2] + sb[3];
}

__global__ void sn_sig_kernel(Ptr6 wp, float* ws){
  const int o[6]    = {64,128,256,512,1024,2048};
  const int cols[6] = {27,72,144,288,576,1152};
  const int toff[6] = {0,27,99,243,531,1107};
  const int bstart[7] = {0,1,2,3,5,9,17};
  int b = blockIdx.x;
  int l = 0; while (l < 5 && b >= bstart[l+1]) l++;
  int chunk = b - bstart[l];
  int r0 = chunk * 256;
  int r1 = min(r0 + 256, o[l]);
  int C = cols[l];
  __shared__ float ts[1152];
  const float* t = ws + WS_OFF_T + toff[l];
  for (int j = threadIdx.x; j < C; j += 256) ts[j] = t[j];
  __syncthreads();
  float zsq = 0.f;
  int r = r0 + (int)threadIdx.x;
  if (r < r1){
    const float* m = wp.p[l] + (size_t)r * C;
    float acc = 0.f;
    for (int j = 0; j < C; j++) acc += m[j] * ts[j];
    zsq = acc * acc;
  }
  __shared__ float sb[4];
  int lane = threadIdx.x & 63, wid = threadIdx.x >> 6;
  for (int off = 32; off; off >>= 1) zsq += __shfl_down(zsq, off, 64);
  if (lane == 0) sb[wid] = zsq;
  __syncthreads();
  if (threadIdx.x == 0) atomicAdd(&ws[WS_OFF_S2 + l], sb[0]+sb[1]+sb[2]+sb[3]);
}

__global__ void wscale_kernel(const float* __restrict__ src, float* __restrict__ dst,
                              int n, const float* __restrict__ tn, const float* __restrict__ s2){
  int i = blockIdx.x * 256 + threadIdx.x;
  if (i >= n) return;
  float inv = sqrtf(tn[0] / s2[0]);
  dst[i] = src[i] * inv;
}

// =================== crop/resize bbox ===================
__global__ void bbox_kernel(const float* __restrict__ img, const float* __restrict__ sem,
                            int* __restrict__ bbox){
  int b = blockIdx.x >> 3;
  int s = blockIdx.x & 7;
  int w = threadIdx.x;
  __shared__ float rowsum[256];
  __shared__ int red[256];
  rowsum[w] = 0.f;
  __syncthreads();
  const float* i0 = img + (size_t)(b*3 + 0) * 65536;
  const float* i1 = i0 + 65536;
  const float* i2 = i1 + 65536;
  const float* mk = sem + (size_t)(b*8 + s) * 65536;
  float colsum = 0.f;
  for (int h = 0; h < 256; h++){
    int off = h*256 + w;
    float v = (i0[off] + i1[off] + i2[off]) * mk[off];
    colsum += v;
    float rv = v;
    for (int o = 32; o; o >>= 1) rv += __shfl_down(rv, o, 64);
    if ((w & 63) == 0) atomicAdd(&rowsum[h], rv);
  }
  __syncthreads();
  red[w] = (colsum != 0.f) ? w : 256; __syncthreads();
  for (int st = 128; st; st >>= 1){ if (w < st) red[w] = min(red[w], red[w+st]); __syncthreads(); }
  int y0 = red[0]; __syncthreads();
  red[w] = (colsum != 0.f) ? w : -1; __syncthreads();
  for (int st = 128; st; st >>= 1){ if (w < st) red[w] = max(red[w], red[w+st]); __syncthreads(); }
  int y1 = red[0]; __syncthreads();
  float rs = rowsum[w];
  red[w] = (rs != 0.f) ? w : 256; __syncthreads();
  for (int st = 128; st; st >>= 1){ if (w < st) red[w] = min(red[w], red[w+st]); __syncthreads(); }
  int x0 = red[0]; __syncthreads();
  red[w] = (rs != 0.f) ? w : -1; __syncthreads();
  for (int st = 128; st; st >>= 1){ if (w < st) red[w] = max(red[w], red[w+st]); __syncthreads(); }
  int x1 = red[0];
  if (w == 0){
    int ok = (y0 < 256) && (x0 < 256);
    int base = blockIdx.x * 4;
    bbox[base+0] = ok ? x0 : 0;
    bbox[base+1] = ok ? (x1 - x0 + 1) : 256;
    bbox[base+2] = ok ? y0 : 0;
    bbox[base+3] = ok ? (y1 - y0 + 1) : 256;
  }
}

__global__ void transimg_kernel(const float* __restrict__ img, const float* __restrict__ sem,
                                const int* __restrict__ bbox, float* __restrict__ out){
  int idx = blockIdx.x * 256 + threadIdx.x;
  int j = idx & 255;
  int i = (idx >> 8) & 255;
  int c = idx >> 16;
  int b = c / 24, ch24 = c % 24;
  int s = ch24 / 3, ch = ch24 % 3;
  const int* bb = bbox + (b*8 + s) * 4;
  int ri = bb[0] + ((i * bb[1]) >> 8);
  int cj = bb[2] + ((j * bb[3]) >> 8);
  float m = sem[((size_t)(b*8 + s) * 256 + ri) * 256 + cj];
  float v = img[((size_t)(b*3 + ch) * 256 + ri) * 256 + cj];
  out[idx] = v * m;
}

// =================== stencil-tiled grouped 3x3 conv (conv1-3, stride 2) ===================
// Block: (b, g, 32x32 out tile, OCC output channels). Input tile + weights in LDS.
// Thread: 4 pixels (16-strided 2x2) x OCC channels.
template<int CIN_G, int CIN_CHUNK, int COUT_G, int OCC, int RELU_IN>
__global__ __launch_bounds__(256) void conv3x3_tile(const float* __restrict__ in,
                                                    const float* __restrict__ wt,
                                                    float* __restrict__ out,
                                                    int Hin, int Hout){
  constexpr int TIH = 65, TIW = 65, RS = 66;
  constexpr int NOC = COUT_G / OCC;
  constexpr int NSTAGE = CIN_G / CIN_CHUNK;
  __shared__ float xs[CIN_CHUNK][TIH][RS];
  __shared__ float wsh[OCC][CIN_CHUNK*9];
  int tid = threadIdx.x;
  int g = blockIdx.y, b = blockIdx.z;
  int ocChunk = blockIdx.x % NOC;
  int tileId  = blockIdx.x / NOC;
  int tilesX = Hout >> 5;
  int tileX = tileId % tilesX, tileY = tileId / tilesX;
  int oh0 = tileY*32, ow0 = tileX*32;
  int ih0 = oh0*2 - 1, iw0 = ow0*2 - 1;
  int sx = tid & 15, sy = tid >> 4;
  const int Cin_tot = CIN_G*8;

  float acc[OCC][2][2];
  #pragma unroll
  for (int o = 0; o < OCC; o++)
    #pragma unroll
    for (int i2 = 0; i2 < 2; i2++)
      #pragma unroll
      for (int j2 = 0; j2 < 2; j2++) acc[o][i2][j2] = 0.f;

  for (int st = 0; st < NSTAGE; st++){
    int icb = st*CIN_CHUNK;
    for (int i = tid; i < CIN_CHUNK*TIH*TIW; i += 256){
      int ic = i / (TIH*TIW);
      int rem = i - ic*(TIH*TIW);
      int r = rem / TIW, c = rem - r*TIW;
      int ih = ih0 + r, iw = iw0 + c;
      float v = 0.f;
      if ((unsigned)ih < (unsigned)Hin && (unsigned)iw < (unsigned)Hin){
        v = in[((size_t)(b*Cin_tot + g*CIN_G + icb + ic)*Hin + ih)*Hin + iw];
        if (RELU_IN) v = (v >= 0.f) ? v : 0.2f*v;
      }
      xs[ic][r][c] = v;
    }
    for (int i = tid; i < OCC*CIN_CHUNK*9; i += 256){
      int o = i / (CIN_CHUNK*9);
      int rr = i - o*(CIN_CHUNK*9);
      int ic = rr / 9, tap = rr - ic*9;
      wsh[o][rr] = wt[((size_t)(g*COUT_G + ocChunk*OCC + o)*CIN_G + icb + ic)*9 + tap];
    }
    __syncthreads();
    #pragma unroll
    for (int ic = 0; ic < CIN_CHUNK; ic++){
      #pragma unroll
      for (int kh = 0; kh < 3; kh++){
        #pragma unroll
        for (int kw = 0; kw < 3; kw++){
          float wv[OCC];
          #pragma unroll
          for (int o = 0; o < OCC; o++) wv[o] = wsh[o][ic*9 + kh*3 + kw];
          #pragma unroll
          for (int i2 = 0; i2 < 2; i2++){
            #pragma unroll
            for (int j2 = 0; j2 < 2; j2++){
              float x = xs[ic][2*(sy + 16*i2) + kh][2*(sx + 16*j2) + kw];
              #pragma unroll
              for (int o = 0; o < OCC; o++) acc[o][i2][j2] += wv[o]*x;
            }
          }
        }
      }
    }
    if (st + 1 < NSTAGE) __syncthreads();
  }

  #pragma unroll
  for (int o = 0; o < OCC; o++){
    int oc = g*COUT_G + ocChunk*OCC + o;
    #pragma unroll
    for (int i2 = 0; i2 < 2; i2++)
      #pragma unroll
      for (int j2 = 0; j2 < 2; j2++){
        int oh = oh0 + sy + 16*i2, ow = ow0 + sx + 16*j2;
        out[((size_t)(b*COUT_G*8 + oc)*Hout + oh)*Hout + ow] = acc[o][i2][j2];
      }
  }
}

// =================== im2col-GEMM grouped 3x3 conv (conv4-6) ===================
// Per (b,g): C[M=COUT_G][N=Hout^2] = W[M][K=CIN_G*9] x im2col(X)[K][N]
template<int STRIDE, int CIN_G, int COUT_G, int HSH>
__global__ __launch_bounds__(256) void conv3x3_gemm(const float* __restrict__ in,
                                                    const float* __restrict__ wt,
                                                    float* __restrict__ out,
                                                    int Hin){
  constexpr int K = CIN_G*9;
  const int Hout = 1 << HSH;
  int z = blockIdx.z; int b = z >> 3, g = z & 7;
  int n0 = blockIdx.x * 64, oc0 = blockIdx.y * 64;
  __shared__ float Ws[16][68];
  __shared__ float Xs[16][68];
  int tid = threadIdx.x;
  int tx = tid & 15, ty = tid >> 4;
  int pixl = tid & 63;
  int kkb = (tid >> 6) << 2;
  float acc[4][4];
  #pragma unroll
  for (int i = 0; i < 4; i++)
    #pragma unroll
    for (int j = 0; j < 4; j++) acc[i][j] = 0.f;

  for (int k0 = 0; k0 < K; k0 += 16){
    #pragma unroll
    for (int r = 0; r < 4; r++){
      int oc_l = (tid >> 4) + 16*r;
      int kk = tid & 15;
      Ws[kk][oc_l] = wt[((size_t)(g*COUT_G + oc0 + oc_l))*K + k0 + kk];
    }
    #pragma unroll
    for (int r = 0; r < 4; r++){
      int kk = kkb + r;
      int k = k0 + kk;               // wave-uniform
      int ic = k / 9, tap = k - ic*9;
      int dh = tap / 3, dw = tap - dh*3;
      int n = n0 + pixl;
      int oh = n >> HSH, ow = n & (Hout - 1);
      int ih = oh*STRIDE - 1 + dh, iw = ow*STRIDE - 1 + dw;
      float v = 0.f;
      if ((unsigned)ih < (unsigned)Hin && (unsigned)iw < (unsigned)Hin){
        v = in[((size_t)(b*CIN_G*8 + g*CIN_G + ic)*Hin + ih)*Hin + iw];
        v = (v >= 0.f) ? v : 0.2f*v;
      }
      Xs[kk][pixl] = v;
    }
    __syncthreads();
    #pragma unroll
    for (int kk = 0; kk < 16; kk++){
      float4 wv = *(const float4*)&Ws[kk][ty*4];
      float4 xv = *(const float4*)&Xs[kk][tx*4];
      acc[0][0] += wv.x*xv.x; acc[0][1] += wv.x*xv.y; acc[0][2] += wv.x*xv.z; acc[0][3] += wv.x*xv.w;
      acc[1][0] += wv.y*xv.x; acc[1][1] += wv.y*xv.y; acc[1][2] += wv.y*xv.z; acc[1][3] += wv.y*xv.w;
      acc[2][0] += wv.z*xv.x; acc[2][1] += wv.z*xv.y; acc[2][2] += wv.z*xv.z; acc[2][3] += wv.z*xv.w;
      acc[3][0] += wv.w*xv.x; acc[3][1] += wv.w*xv.y; acc[3][2] += wv.w*xv.z; acc[3][3] += wv.w*xv.w;
    }
    __syncthreads();
  }

  #pragma unroll
  for (int i = 0; i < 4; i++){
    int oc = g*COUT_G + oc0 + ty*4 + i;
    #pragma unroll
    for (int j = 0; j < 4; j++){
      int n = n0 + tx*4 + j;
      int oh = n >> HSH, ow = n & (Hout - 1);
      out[((size_t)(b*COUT_G*8 + oc)*Hout + oh)*Hout + ow] = acc[i][j];
    }
  }
}

// =================== instance norm ===================
__global__ void inorm_kernel(const float* __restrict__ in, float* __restrict__ out,
                             int N, int relu_out){
  int bc = blockIdx.x;
  const float* p = in + (size_t)bc * N;
  float* q = out + (size_t)bc * N;
  float s = 0.f, ss = 0.f;
  for (int i = threadIdx.x; i < N; i += blockDim.x){ float x = p[i]; s += x; ss += x*x; }
  __shared__ float sb[8];
  int lane = threadIdx.x & 63, wid = threadIdx.x >> 6;
  for (int o = 32; o; o >>= 1){ s += __shfl_down(s, o, 64); ss += __shfl_down(ss, o, 64); }
  if (lane == 0){ sb[wid] = s; sb[4 + wid] = ss; }
  __syncthreads();
  if (threadIdx.x == 0){
    int nw = blockDim.x >> 6;
    float S = 0.f, SS = 0.f;
    for (int i = 0; i < nw; i++){ S += sb[i]; SS += sb[4+i]; }
    float mean = S / N;
    float var = SS / N - mean*mean;
    sb[0] = mean;
    sb[4] = rsqrtf(var + 1e-5f);
  }
  __syncthreads();
  float mean = sb[0], r = sb[4];
  for (int i = threadIdx.x; i < N; i += blockDim.x){
    float y = (p[i] - mean) * r;
    if (relu_out) y = (y >= 0.f) ? y : 0.2f*y;
    q[i] = y;
  }
}

// =================== 1x1 conv as tiled GEMM (interior of padded output) ===================
__global__ __launch_bounds__(256) void conv1x1_gemm(const float* __restrict__ in,
                                                    const float* __restrict__ wt,
                                                    const float* __restrict__ bias,
                                                    float* __restrict__ out,
                                                    int Cin, int H){
  int HW = H * H;
  int b   = blockIdx.z;
  int oc0 = blockIdx.y * 64;
  int pix0 = blockIdx.x * 64;
  __shared__ float Ws[16][68];
  __shared__ float Xs[16][68];
  int tid = threadIdx.x;
  int tx = tid & 15, ty = tid >> 4;
  float acc[4][4];
  #pragma unroll
  for (int i = 0; i < 4; i++)
    #pragma unroll
    for (int j = 0; j < 4; j++) acc[i][j] = 0.f;

  for (int k0 = 0; k0 < Cin; k0 += 16){
    #pragma unroll
    for (int r = 0; r < 4; r++){
      int oc_l = (tid >> 4) + 16*r;
      int kk = tid & 15;
      Ws[kk][oc_l] = wt[(size_t)(oc0 + oc_l) * Cin + k0 + kk];
    }
    {
      int pixl = tid & 63;
      int kkb = (tid >> 6) << 2;
      #pragma unroll
      for (int r = 0; r < 4; r++){
        int kk = kkb + r;
        float x = in[(size_t)(b * Cin + k0 + kk) * HW + pix0 + pixl];
        Xs[kk][pixl] = (x >= 0.f) ? x : 0.2f*x;
      }
    }
    __syncthreads();
    #pragma unroll
    for (int kk = 0; kk < 16; kk++){
      float4 wv = *(const float4*)&Ws[kk][ty*4];
      float4 xv = *(const float4*)&Xs[kk][tx*4];
      acc[0][0] += wv.x*xv.x; acc[0][1] += wv.x*xv.y; acc[0][2] += wv.x*xv.z; acc[0][3] += wv.x*xv.w;
      acc[1][0] += wv.y*xv.x; acc[1][1] += wv.y*xv.y; acc[1][2] += wv.y*xv.z; acc[1][3] += wv.y*xv.w;
      acc[2][0] += wv.z*xv.x; acc[2][1] += wv.z*xv.y; acc[2][2] += wv.z*xv.z; acc[2][3] += wv.z*xv.w;
      acc[3][0] += wv.w*xv.x; acc[3][1] += wv.w*xv.y; acc[3][2] += wv.w*xv.z; acc[3][3] += wv.w*xv.w;
    }
    __syncthreads();
  }

  int Wp = H + 2;
  #pragma unroll
  for (int i = 0; i < 4; i++){
    int oc = oc0 + ty*4 + i;
    float bv = bias[oc];
    #pragma unroll
    for (int j = 0; j < 4; j++){
      int pix = pix0 + tx*4 + j;
      int ph = pix / H, pw = pix % H;
      float v = acc[i][j] + bv;
      v = (v >= 0.f) ? v : 0.2f*v;
      out[(((size_t)b*2048 + oc)*Wp + ph + 1)*Wp + pw + 1] = v;
    }
  }
}

// border cells only: out[b][oc][border of (H+2)x(H+2)] = lrelu(bias[oc])
__global__ void border_kernel(const float* __restrict__ bias, float* __restrict__ out, int H){
  int Wp = H + 2, perim = 4*Wp - 4;
  int p = threadIdx.x;
  if (p >= perim) return;
  int oc = blockIdx.y, b = blockIdx.z;
  int ph, pw;
  if (p < Wp){ ph = 0; pw = p; }
  else if (p < 2*Wp){ ph = Wp - 1; pw = p - Wp; }
  else { int q = p - 2*Wp; ph = 1 + (q >> 1); pw = (q & 1) ? (Wp - 1) : 0; }
  float bv = bias[oc];
  bv = (bv >= 0.f) ? bv : 0.2f*bv;
  out[(((size_t)b*2048 + oc)*Wp + ph)*Wp + pw] = bv;
}

// =================== host ===================
extern "C" void kernel_launch(void* const* d_in, const int* in_sizes, int n_in,
                              void* d_out, int out_size, void* d_ws, size_t ws_size,
                              hipStream_t stream){
  const float* img = (const float*)d_in[0];
  const float* sem = (const float*)d_in[1];
  Ptr6 wp;
  for (int l = 0; l < 6; l++) wp.p[l] = (const float*)d_in[2 + l];
  const float* gw1 = (const float*)d_in[8];
  const float* gb1 = (const float*)d_in[9];
  const float* gw2 = (const float*)d_in[10];
  const float* gb2 = (const float*)d_in[11];
  float* out = (float*)d_out;
  float* ws  = (float*)d_ws;

  float* bufA = out + OUT_X2;
  float* bufB = bufA + 8388608;
  float* bufC = ws + WS_OFF_C;
  float* bufD = ws + WS_OFF_D;
  int* bbox = (int*)(ws + WS_OFF_BBOX);

  static const int kWOff[6]  = {0,1728,10944,47808,195264,785088};
  static const int kWSize[6] = {1728,9216,36864,147456,589824,2359296};

  hipMemsetAsync(ws + WS_OFF_T, 0, (WS_OFF_S2 + 8 - WS_OFF_T) * sizeof(float), stream);

  gen_u_par<<<6, 256, 0, stream>>>(ws);
  sn_t_kernel<<<32, 256, 0, stream>>>(wp, ws);
  sn_tn_kernel<<<6, 256, 0, stream>>>(ws);
  sn_sig_kernel<<<17, 256, 0, stream>>>(wp, ws);
  for (int l = 0; l < 6; l++)
    wscale_kernel<<<(kWSize[l]+255)/256, 256, 0, stream>>>(wp.p[l], ws + WS_OFF_W + kWOff[l],
                                                           kWSize[l], ws + WS_OFF_TN + l, ws + WS_OFF_S2 + l);

  bbox_kernel<<<64, 256, 0, stream>>>(img, sem, bbox);
  transimg_kernel<<<49152, 256, 0, stream>>>(img, sem, bbox, out + OUT_IMG);

  // conv1: images(8,24,256,256) -> (8,64,128,128)   [stencil tile]
  conv3x3_tile<3,3,8,8,0><<<dim3(16,8,8), 256, 0, stream>>>(out + OUT_IMG, ws + WS_OFF_W + kWOff[0],
                                                            bufA, 256, 128);
  inorm_kernel<<<512, 256, 0, stream>>>(bufA, bufB, 16384, 0);
  // conv2 -> (8,128,64,64)
  conv3x3_tile<8,2,16,16,1><<<dim3(4,8,8), 256, 0, stream>>>(bufB, ws + WS_OFF_W + kWOff[1],
                                                             bufA, 128, 64);
  inorm_kernel<<<1024, 256, 0, stream>>>(bufA, bufB, 4096, 0);
  // conv3 -> out_8 (8,256,32,32)
  conv3x3_tile<16,2,32,8,1><<<dim3(4,8,8), 256, 0, stream>>>(bufB, ws + WS_OFF_W + kWOff[2],
                                                             bufA, 64, 32);
  inorm_kernel<<<2048, 256, 0, stream>>>(bufA, bufC, 1024, 0);
  // conv4 -> out_16 (8,512,16,16)   [im2col gemm]
  conv3x3_gemm<2,32,64,4><<<dim3(4,1,64), 256, 0, stream>>>(bufC, ws + WS_OFF_W + kWOff[3], bufA, 32);
  inorm_kernel<<<4096, 256, 0, stream>>>(bufA, bufD, 256, 0);
  // conv5 -> out_32 (8,1024,8,8)
  conv3x3_gemm<2,64,128,3><<<dim3(1,2,64), 256, 0, stream>>>(bufD, ws + WS_OFF_W + kWOff[4], bufA, 16);
  inorm_kernel<<<8192, 64, 0, stream>>>(bufA, bufB, 64, 0);
  // conv6 -> (8,2048,8,8), stride 1
  conv3x3_gemm<1,128,256,3><<<dim3(1,4,64), 256, 0, stream>>>(bufB, ws + WS_OFF_W + kWOff[5], bufA, 8);
  inorm_kernel<<<16384, 64, 0, stream>>>(bufA, out + OUT_X, 64, 1);   // x

  // x_1 -> (8,2048,18,18)
  border_kernel<<<dim3(1,2048,8), 256, 0, stream>>>(gb1, out + OUT_X1, 16);
  conv1x1_gemm<<<dim3(4, 32, 8), 256, 0, stream>>>(bufD, gw1, gb1, out + OUT_X1, 512, 16);
  // x_2 -> (8,2048,34,34)
  border_kernel<<<dim3(1,2048,8), 256, 0, stream>>>(gb2, out + OUT_X2, 32);
  conv1x1_gemm<<<dim3(16, 32, 8), 256, 0, stream>>>(bufC, gw2, gb2, out + OUT_X2, 256, 32);
}

// Round 5
// 1164.973 us; speedup vs baseline: 5.7971x; 1.2309x over previous
//
#include <hip/hip_runtime.h>
#include <math.h>

// ---------------- workspace layout (float indices) ----------------
#define WS_OFF_U     0
#define WS_OFF_T     4096
#define WS_OFF_TN    6400
#define WS_OFF_S2    6408
#define WS_OFF_BBOX  6416
#define WS_OFF_W     8192
#define WS_OFF_C     3152896  // out_8 normalized (2,097,152)
#define WS_OFF_D     5250048  // out_16 normalized (1,048,576)

// ---------------- d_out layout (float offsets) ----------------
#define OUT_X    0          // 8*2048*8*8     = 1,048,576
#define OUT_X1   1048576    // 8*2048*18*18   = 5,308,416
#define OUT_X2   6356992    // 8*2048*34*34   = 18,939,904 (hosts bufA/bufB scratch)
#define OUT_IMG  25296896   // 8*24*256*256   = 12,582,912

struct Ptr6 { const float* p[6]; };

// =================== parallel MT19937 + Marsaglia polar (numpy RandomState) ===================
#define MT_UP 0x80000000u
#define MT_LO 0x7fffffffu

__global__ __launch_bounds__(256) void gen_u_par(float* ws){
  const int os[6]   = {64,128,256,512,1024,2048};
  const int uoff[6] = {0,64,192,448,960,1984};
  int l = blockIdx.x;
  int n = os[l];
  int tid = threadIdx.x;

  __shared__ unsigned mt[624];
  __shared__ unsigned draws[8192];
  __shared__ float px[2048], py[2048];
  __shared__ unsigned char accf[2048];
  __shared__ int scan[256];

  if (tid == 0){
    unsigned seed = (unsigned)(l + 1);
    for (int i = 0; i < 624; i++){
      mt[i] = seed;
      seed = 1812433253u * (seed ^ (seed >> 30)) + (unsigned)(i + 1);
    }
  }
  __syncthreads();

  int need = 4 * n;
  int twists = (need + 623) / 624;
  for (int t = 0; t < twists; t++){
    unsigned yA = 0, vA = 0;
    if (tid < 227){ yA = (mt[tid] & MT_UP) | (mt[tid+1] & MT_LO); vA = mt[tid+397]; }
    __syncthreads();
    if (tid < 227){ mt[tid] = vA ^ (yA >> 1) ^ ((yA & 1u) ? 0x9908b0dfu : 0u); }
    __syncthreads();
    unsigned yB = 0, vB = 0; int iB = 227 + tid;
    if (tid < 227){ yB = (mt[iB] & MT_UP) | (mt[iB+1] & MT_LO); vB = mt[iB-227]; }
    __syncthreads();
    if (tid < 227){ mt[iB] = vB ^ (yB >> 1) ^ ((yB & 1u) ? 0x9908b0dfu : 0u); }
    __syncthreads();
    unsigned yC = 0, vC = 0; int iC = 454 + tid;
    if (tid < 169){ yC = (mt[iC] & MT_UP) | (mt[iC+1] & MT_LO); vC = mt[iC-227]; }
    __syncthreads();
    if (tid < 169){ mt[iC] = vC ^ (yC >> 1) ^ ((yC & 1u) ? 0x9908b0dfu : 0u); }
    __syncthreads();
    if (tid == 0){
      unsigned y = (mt[623] & MT_UP) | (mt[0] & MT_LO);
      mt[623] = mt[396] ^ (y >> 1) ^ ((y & 1u) ? 0x9908b0dfu : 0u);
    }
    __syncthreads();
    for (int i = tid; i < 624; i += 256){
      int pos = t * 624 + i;
      if (pos < need){
        unsigned y = mt[i];
        y ^= y >> 11; y ^= (y << 7) & 0x9d2c5680u; y ^= (y << 15) & 0xefc60000u; y ^= y >> 18;
        draws[pos] = y;
      }
    }
    __syncthreads();
  }

  int A = (n + 255) / 256;
  int local = 0;
  for (int a = 0; a < A; a++){
    int k = tid * A + a;
    if (k < n){
      double u1 = ((draws[4*k]   >> 5) * 67108864.0 + (draws[4*k+1] >> 6)) / 9007199254740992.0;
      double u2 = ((draws[4*k+2] >> 5) * 67108864.0 + (draws[4*k+3] >> 6)) / 9007199254740992.0;
      double x1 = 2.0*u1 - 1.0, x2 = 2.0*u2 - 1.0;
      double r2 = x1*x1 + x2*x2;
      int ok = (r2 < 1.0 && r2 != 0.0);
      accf[k] = (unsigned char)ok;
      if (ok){
        double f = sqrt(-2.0 * log(r2) / r2);
        px[k] = (float)(f * x2);
        py[k] = (float)(f * x1);
      }
      local += ok;
    }
  }
  scan[tid] = local;
  __syncthreads();
  if (tid == 0){
    int run = 0;
    for (int i = 0; i < 256; i++){ int c = scan[i]; scan[i] = run; run += c; }
  }
  __syncthreads();
  int j = scan[tid];
  float* u = ws + WS_OFF_U + uoff[l];
  for (int a = 0; a < A; a++){
    int k = tid * A + a;
    if (k < n && accf[k]){
      if (2*j + 1 < n){ u[2*j] = px[k]; u[2*j+1] = py[k]; }
      j++;
    }
  }
}

// =================== spectral norm: t = M^T u ===================
// Block = (layer, 16-row chunk). 252 blocks. Coalesced column reads, 16 unrolled
// independent row-loads per column, one atomicAdd per (column, chunk).
__global__ __launch_bounds__(256) void sn_t_kernel(Ptr6 wp, float* ws){
  const int cols[6] = {27,72,144,288,576,1152};
  const int uoff[6] = {0,64,192,448,960,1984};
  const int toff[6] = {0,27,99,243,531,1107};
  const int cstart[7] = {0,4,12,28,60,124,252};   // 16-row chunks per layer
  int b = blockIdx.x;
  int l = 0; while (l < 5 && b >= cstart[l+1]) l++;
  int chunk = b - cstart[l];
  int r0 = chunk * 16;
  int C = cols[l];
  const float* m = wp.p[l];
  const float* u = ws + WS_OFF_U + uoff[l];
  float* t = ws + WS_OFF_T + toff[l];
  __shared__ float us[16];
  if (threadIdx.x < 16) us[threadIdx.x] = u[r0 + threadIdx.x];
  __syncthreads();
  for (int j = threadIdx.x; j < C; j += 256){
    float acc = 0.f;
    #pragma unroll
    for (int r = 0; r < 16; r++) acc += m[(size_t)(r0 + r) * C + j] * us[r];
    atomicAdd(&t[j], acc);
  }
}

__global__ void sn_tn_kernel(float* ws){
  const int cols[6] = {27,72,144,288,576,1152};
  const int toff[6] = {0,27,99,243,531,1107};
  int l = blockIdx.x;
  const float* t = ws + WS_OFF_T + toff[l];
  float s = 0.f;
  for (int j = threadIdx.x; j < cols[l]; j += 256){ float v = t[j]; s += v*v; }
  __shared__ float sb[4];
  int lane = threadIdx.x & 63, wid = threadIdx.x >> 6;
  for (int o = 32; o; o >>= 1) s += __shfl_down(s, o, 64);
  if (lane == 0) sb[wid] = s;
  __syncthreads();
  if (threadIdx.x == 0) ws[WS_OFF_TN + l] = sb[0] + sb[1] + sb[2] + sb[3];
}

// =================== spectral norm: s2 += ||M t||^2, wave-per-row ===================
// 4032 rows total; one 64-lane wave per row (coalesced column strides);
// LDS-staged per-layer partial, <=6 global atomics per block.
__global__ __launch_bounds__(256) void sn_z_kernel(Ptr6 wp, float* ws){
  const int cols[6] = {27,72,144,288,576,1152};
  const int toff[6] = {0,27,99,243,531,1107};
  const int rstart[7] = {0,64,192,448,960,1984,4032};
  __shared__ float part[6];
  if (threadIdx.x < 6) part[threadIdx.x] = 0.f;
  __syncthreads();
  int gr = blockIdx.x * 4 + (threadIdx.x >> 6);
  int lane = threadIdx.x & 63;
  if (gr < 4032){
    int l = 0; while (l < 5 && gr >= rstart[l+1]) l++;
    int row = gr - rstart[l];
    int C = cols[l];
    const float* m = wp.p[l] + (size_t)row * C;
    const float* t = ws + WS_OFF_T + toff[l];
    float acc = 0.f;
    for (int c = lane; c < C; c += 64) acc += m[c] * t[c];
    for (int o = 32; o; o >>= 1) acc += __shfl_down(acc, o, 64);
    if (lane == 0) atomicAdd(&part[l], acc * acc);
  }
  __syncthreads();
  if (threadIdx.x < 6 && part[threadIdx.x] != 0.f)
    atomicAdd(&ws[WS_OFF_S2 + threadIdx.x], part[threadIdx.x]);
}

__global__ void wscale_kernel(const float* __restrict__ src, float* __restrict__ dst,
                              int n, const float* __restrict__ tn, const float* __restrict__ s2){
  int i = blockIdx.x * 256 + threadIdx.x;
  if (i >= n) return;
  float inv = sqrtf(tn[0] / s2[0]);
  dst[i] = src[i] * inv;
}

// =================== crop/resize bbox ===================
__global__ void bbox_kernel(const float* __restrict__ img, const float* __restrict__ sem,
                            int* __restrict__ bbox){
  int b = blockIdx.x >> 3;
  int s = blockIdx.x & 7;
  int w = threadIdx.x;
  __shared__ float rowsum[256];
  __shared__ int red[256];
  rowsum[w] = 0.f;
  __syncthreads();
  const float* i0 = img + (size_t)(b*3 + 0) * 65536;
  const float* i1 = i0 + 65536;
  const float* i2 = i1 + 65536;
  const float* mk = sem + (size_t)(b*8 + s) * 65536;
  float colsum = 0.f;
  for (int h = 0; h < 256; h++){
    int off = h*256 + w;
    float v = (i0[off] + i1[off] + i2[off]) * mk[off];
    colsum += v;
    float rv = v;
    for (int o = 32; o; o >>= 1) rv += __shfl_down(rv, o, 64);
    if ((w & 63) == 0) atomicAdd(&rowsum[h], rv);
  }
  __syncthreads();
  red[w] = (colsum != 0.f) ? w : 256; __syncthreads();
  for (int st = 128; st; st >>= 1){ if (w < st) red[w] = min(red[w], red[w+st]); __syncthreads(); }
  int y0 = red[0]; __syncthreads();
  red[w] = (colsum != 0.f) ? w : -1; __syncthreads();
  for (int st = 128; st; st >>= 1){ if (w < st) red[w] = max(red[w], red[w+st]); __syncthreads(); }
  int y1 = red[0]; __syncthreads();
  float rs = rowsum[w];
  red[w] = (rs != 0.f) ? w : 256; __syncthreads();
  for (int st = 128; st; st >>= 1){ if (w < st) red[w] = min(red[w], red[w+st]); __syncthreads(); }
  int x0 = red[0]; __syncthreads();
  red[w] = (rs != 0.f) ? w : -1; __syncthreads();
  for (int st = 128; st; st >>= 1){ if (w < st) red[w] = max(red[w], red[w+st]); __syncthreads(); }
  int x1 = red[0];
  if (w == 0){
    int ok = (y0 < 256) && (x0 < 256);
    int base = blockIdx.x * 4;
    bbox[base+0] = ok ? x0 : 0;
    bbox[base+1] = ok ? (x1 - x0 + 1) : 256;
    bbox[base+2] = ok ? y0 : 0;
    bbox[base+3] = ok ? (y1 - y0 + 1) : 256;
  }
}

__global__ void transimg_kernel(const float* __restrict__ img, const float* __restrict__ sem,
                                const int* __restrict__ bbox, float* __restrict__ out){
  int idx = blockIdx.x * 256 + threadIdx.x;
  int j = idx & 255;
  int i = (idx >> 8) & 255;
  int c = idx >> 16;
  int b = c / 24, ch24 = c % 24;
  int s = ch24 / 3, ch = ch24 % 3;
  const int* bb = bbox + (b*8 + s) * 4;
  int ri = bb[0] + ((i * bb[1]) >> 8);
  int cj = bb[2] + ((j * bb[3]) >> 8);
  float m = sem[((size_t)(b*8 + s) * 256 + ri) * 256 + cj];
  float v = img[((size_t)(b*3 + ch) * 256 + ri) * 256 + cj];
  out[idx] = v * m;
}

// =================== stencil-tiled grouped 3x3 conv (conv1-3, stride 2) ===================
template<int CIN_G, int CIN_CHUNK, int COUT_G, int OCC, int RELU_IN>
__global__ __launch_bounds__(256) void conv3x3_tile(const float* __restrict__ in,
                                                    const float* __restrict__ wt,
                                                    float* __restrict__ out,
                                                    int Hin, int Hout){
  constexpr int TIH = 65, TIW = 65, RS = 66;
  constexpr int NOC = COUT_G / OCC;
  constexpr int NSTAGE = CIN_G / CIN_CHUNK;
  __shared__ float xs[CIN_CHUNK][TIH][RS];
  __shared__ float wsh[OCC][CIN_CHUNK*9];
  int tid = threadIdx.x;
  int g = blockIdx.y, b = blockIdx.z;
  int ocChunk = blockIdx.x % NOC;
  int tileId  = blockIdx.x / NOC;
  int tilesX = Hout >> 5;
  int tileX = tileId % tilesX, tileY = tileId / tilesX;
  int oh0 = tileY*32, ow0 = tileX*32;
  int ih0 = oh0*2 - 1, iw0 = ow0*2 - 1;
  int sx = tid & 15, sy = tid >> 4;
  const int Cin_tot = CIN_G*8;

  float acc[OCC][2][2];
  #pragma unroll
  for (int o = 0; o < OCC; o++)
    #pragma unroll
    for (int i2 = 0; i2 < 2; i2++)
      #pragma unroll
      for (int j2 = 0; j2 < 2; j2++) acc[o][i2][j2] = 0.f;

  for (int st = 0; st < NSTAGE; st++){
    int icb = st*CIN_CHUNK;
    for (int i = tid; i < CIN_CHUNK*TIH*TIW; i += 256){
      int ic = i / (TIH*TIW);
      int rem = i - ic*(TIH*TIW);
      int r = rem / TIW, c = rem - r*TIW;
      int ih = ih0 + r, iw = iw0 + c;
      float v = 0.f;
      if ((unsigned)ih < (unsigned)Hin && (unsigned)iw < (unsigned)Hin){
        v = in[((size_t)(b*Cin_tot + g*CIN_G + icb + ic)*Hin + ih)*Hin + iw];
        if (RELU_IN) v = (v >= 0.f) ? v : 0.2f*v;
      }
      xs[ic][r][c] = v;
    }
    for (int i = tid; i < OCC*CIN_CHUNK*9; i += 256){
      int o = i / (CIN_CHUNK*9);
      int rr = i - o*(CIN_CHUNK*9);
      int ic = rr / 9, tap = rr - ic*9;
      wsh[o][rr] = wt[((size_t)(g*COUT_G + ocChunk*OCC + o)*CIN_G + icb + ic)*9 + tap];
    }
    __syncthreads();
    #pragma unroll
    for (int ic = 0; ic < CIN_CHUNK; ic++){
      #pragma unroll
      for (int kh = 0; kh < 3; kh++){
        #pragma unroll
        for (int kw = 0; kw < 3; kw++){
          float wv[OCC];
          #pragma unroll
          for (int o = 0; o < OCC; o++) wv[o] = wsh[o][ic*9 + kh*3 + kw];
          #pragma unroll
          for (int i2 = 0; i2 < 2; i2++){
            #pragma unroll
            for (int j2 = 0; j2 < 2; j2++){
              float x = xs[ic][2*(sy + 16*i2) + kh][2*(sx + 16*j2) + kw];
              #pragma unroll
              for (int o = 0; o < OCC; o++) acc[o][i2][j2] += wv[o]*x;
            }
          }
        }
      }
    }
    if (st + 1 < NSTAGE) __syncthreads();
  }

  #pragma unroll
  for (int o = 0; o < OCC; o++){
    int oc = g*COUT_G + ocChunk*OCC + o;
    #pragma unroll
    for (int i2 = 0; i2 < 2; i2++)
      #pragma unroll
      for (int j2 = 0; j2 < 2; j2++){
        int oh = oh0 + sy + 16*i2, ow = ow0 + sx + 16*j2;
        out[((size_t)(b*COUT_G*8 + oc)*Hout + oh)*Hout + ow] = acc[o][i2][j2];
      }
  }
}

// =================== im2col-GEMM grouped 3x3 conv (conv4-6) ===================
template<int STRIDE, int CIN_G, int COUT_G, int HSH>
__global__ __launch_bounds__(256) void conv3x3_gemm(const float* __restrict__ in,
                                                    const float* __restrict__ wt,
                                                    float* __restrict__ out,
                                                    int Hin){
  constexpr int K = CIN_G*9;
  const int Hout = 1 << HSH;
  int z = blockIdx.z; int b = z >> 3, g = z & 7;
  int n0 = blockIdx.x * 64, oc0 = blockIdx.y * 64;
  __shared__ float Ws[16][68];
  __shared__ float Xs[16][68];
  int tid = threadIdx.x;
  int tx = tid & 15, ty = tid >> 4;
  int pixl = tid & 63;
  int kkb = (tid >> 6) << 2;
  float acc[4][4];
  #pragma unroll
  for (int i = 0; i < 4; i++)
    #pragma unroll
    for (int j = 0; j < 4; j++) acc[i][j] = 0.f;

  for (int k0 = 0; k0 < K; k0 += 16){
    #pragma unroll
    for (int r = 0; r < 4; r++){
      int oc_l = (tid >> 4) + 16*r;
      int kk = tid & 15;
      Ws[kk][oc_l] = wt[((size_t)(g*COUT_G + oc0 + oc_l))*K + k0 + kk];
    }
    #pragma unroll
    for (int r = 0; r < 4; r++){
      int kk = kkb + r;
      int k = k0 + kk;
      int ic = k / 9, tap = k - ic*9;
      int dh = tap / 3, dw = tap - dh*3;
      int n = n0 + pixl;
      int oh = n >> HSH, ow = n & (Hout - 1);
      int ih = oh*STRIDE - 1 + dh, iw = ow*STRIDE - 1 + dw;
      float v = 0.f;
      if ((unsigned)ih < (unsigned)Hin && (unsigned)iw < (unsigned)Hin){
        v = in[((size_t)(b*CIN_G*8 + g*CIN_G + ic)*Hin + ih)*Hin + iw];
        v = (v >= 0.f) ? v : 0.2f*v;
      }
      Xs[kk][pixl] = v;
    }
    __syncthreads();
    #pragma unroll
    for (int kk = 0; kk < 16; kk++){
      float4 wv = *(const float4*)&Ws[kk][ty*4];
      float4 xv = *(const float4*)&Xs[kk][tx*4];
      acc[0][0] += wv.x*xv.x; acc[0][1] += wv.x*xv.y; acc[0][2] += wv.x*xv.z; acc[0][3] += wv.x*xv.w;
      acc[1][0] += wv.y*xv.x; acc[1][1] += wv.y*xv.y; acc[1][2] += wv.y*xv.z; acc[1][3] += wv.y*xv.w;
      acc[2][0] += wv.z*xv.x; acc[2][1] += wv.z*xv.y; acc[2][2] += wv.z*xv.z; acc[2][3] += wv.z*xv.w;
      acc[3][0] += wv.w*xv.x; acc[3][1] += wv.w*xv.y; acc[3][2] += wv.w*xv.z; acc[3][3] += wv.w*xv.w;
    }
    __syncthreads();
  }

  #pragma unroll
  for (int i = 0; i < 4; i++){
    int oc = g*COUT_G + oc0 + ty*4 + i;
    #pragma unroll
    for (int j = 0; j < 4; j++){
      int n = n0 + tx*4 + j;
      int oh = n >> HSH, ow = n & (Hout - 1);
      out[((size_t)(b*COUT_G*8 + oc)*Hout + oh)*Hout + ow] = acc[i][j];
    }
  }
}

// =================== instance norm ===================
__global__ void inorm_kernel(const float* __restrict__ in, float* __restrict__ out,
                             int N, int relu_out){
  int bc = blockIdx.x;
  const float* p = in + (size_t)bc * N;
  float* q = out + (size_t)bc * N;
  float s = 0.f, ss = 0.f;
  for (int i = threadIdx.x; i < N; i += blockDim.x){ float x = p[i]; s += x; ss += x*x; }
  __shared__ float sb[8];
  int lane = threadIdx.x & 63, wid = threadIdx.x >> 6;
  for (int o = 32; o; o >>= 1){ s += __shfl_down(s, o, 64); ss += __shfl_down(ss, o, 64); }
  if (lane == 0){ sb[wid] = s; sb[4 + wid] = ss; }
  __syncthreads();
  if (threadIdx.x == 0){
    int nw = blockDim.x >> 6;
    float S = 0.f, SS = 0.f;
    for (int i = 0; i < nw; i++){ S += sb[i]; SS += sb[4+i]; }
    float mean = S / N;
    float var = SS / N - mean*mean;
    sb[0] = mean;
    sb[4] = rsqrtf(var + 1e-5f);
  }
  __syncthreads();
  float mean = sb[0], r = sb[4];
  for (int i = threadIdx.x; i < N; i += blockDim.x){
    float y = (p[i] - mean) * r;
    if (relu_out) y = (y >= 0.f) ? y : 0.2f*y;
    q[i] = y;
  }
}

// =================== 1x1 conv as tiled GEMM (interior of padded output) ===================
__global__ __launch_bounds__(256) void conv1x1_gemm(const float* __restrict__ in,
                                                    const float* __restrict__ wt,
                                                    const float* __restrict__ bias,
                                                    float* __restrict__ out,
                                                    int Cin, int H){
  int HW = H * H;
  int b   = blockIdx.z;
  int oc0 = blockIdx.y * 64;
  int pix0 = blockIdx.x * 64;
  __shared__ float Ws[16][68];
  __shared__ float Xs[16][68];
  int tid = threadIdx.x;
  int tx = tid & 15, ty = tid >> 4;
  float acc[4][4];
  #pragma unroll
  for (int i = 0; i < 4; i++)
    #pragma unroll
    for (int j = 0; j < 4; j++) acc[i][j] = 0.f;

  for (int k0 = 0; k0 < Cin; k0 += 16){
    #pragma unroll
    for (int r = 0; r < 4; r++){
      int oc_l = (tid >> 4) + 16*r;
      int kk = tid & 15;
      Ws[kk][oc_l] = wt[(size_t)(oc0 + oc_l) * Cin + k0 + kk];
    }
    {
      int pixl = tid & 63;
      int kkb = (tid >> 6) << 2;
      #pragma unroll
      for (int r = 0; r < 4; r++){
        int kk = kkb + r;
        float x = in[(size_t)(b * Cin + k0 + kk) * HW + pix0 + pixl];
        Xs[kk][pixl] = (x >= 0.f) ? x : 0.2f*x;
      }
    }
    __syncthreads();
    #pragma unroll
    for (int kk = 0; kk < 16; kk++){
      float4 wv = *(const float4*)&Ws[kk][ty*4];
      float4 xv = *(const float4*)&Xs[kk][tx*4];
      acc[0][0] += wv.x*xv.x; acc[0][1] += wv.x*xv.y; acc[0][2] += wv.x*xv.z; acc[0][3] += wv.x*xv.w;
      acc[1][0] += wv.y*xv.x; acc[1][1] += wv.y*xv.y; acc[1][2] += wv.y*xv.z; acc[1][3] += wv.y*xv.w;
      acc[2][0] += wv.z*xv.x; acc[2][1] += wv.z*xv.y; acc[2][2] += wv.z*xv.z; acc[2][3] += wv.z*xv.w;
      acc[3][0] += wv.w*xv.x; acc[3][1] += wv.w*xv.y; acc[3][2] += wv.w*xv.z; acc[3][3] += wv.w*xv.w;
    }
    __syncthreads();
  }

  int Wp = H + 2;
  #pragma unroll
  for (int i = 0; i < 4; i++){
    int oc = oc0 + ty*4 + i;
    float bv = bias[oc];
    #pragma unroll
    for (int j = 0; j < 4; j++){
      int pix = pix0 + tx*4 + j;
      int ph = pix / H, pw = pix % H;
      float v = acc[i][j] + bv;
      v = (v >= 0.f) ? v : 0.2f*v;
      out[(((size_t)b*2048 + oc)*Wp + ph + 1)*Wp + pw + 1] = v;
    }
  }
}

// border cells only: out[b][oc][border of (H+2)x(H+2)] = lrelu(bias[oc])
__global__ void border_kernel(const float* __restrict__ bias, float* __restrict__ out, int H){
  int Wp = H + 2, perim = 4*Wp - 4;
  int p = threadIdx.x;
  if (p >= perim) return;
  int oc = blockIdx.y, b = blockIdx.z;
  int ph, pw;
  if (p < Wp){ ph = 0; pw = p; }
  else if (p < 2*Wp){ ph = Wp - 1; pw = p - Wp; }
  else { int q = p - 2*Wp; ph = 1 + (q >> 1); pw = (q & 1) ? (Wp - 1) : 0; }
  float bv = bias[oc];
  bv = (bv >= 0.f) ? bv : 0.2f*bv;
  out[(((size_t)b*2048 + oc)*Wp + ph)*Wp + pw] = bv;
}

// =================== host ===================
extern "C" void kernel_launch(void* const* d_in, const int* in_sizes, int n_in,
                              void* d_out, int out_size, void* d_ws, size_t ws_size,
                              hipStream_t stream){
  const float* img = (const float*)d_in[0];
  const float* sem = (const float*)d_in[1];
  Ptr6 wp;
  for (int l = 0; l < 6; l++) wp.p[l] = (const float*)d_in[2 + l];
  const float* gw1 = (const float*)d_in[8];
  const float* gb1 = (const float*)d_in[9];
  const float* gw2 = (const float*)d_in[10];
  const float* gb2 = (const float*)d_in[11];
  float* out = (float*)d_out;
  float* ws  = (float*)d_ws;

  float* bufA = out + OUT_X2;
  float* bufB = bufA + 8388608;
  float* bufC = ws + WS_OFF_C;
  float* bufD = ws + WS_OFF_D;
  int* bbox = (int*)(ws + WS_OFF_BBOX);

  static const int kWOff[6]  = {0,1728,10944,47808,195264,785088};
  static const int kWSize[6] = {1728,9216,36864,147456,589824,2359296};

  hipMemsetAsync(ws + WS_OFF_T, 0, (WS_OFF_S2 + 8 - WS_OFF_T) * sizeof(float), stream);

  gen_u_par<<<6, 256, 0, stream>>>(ws);
  sn_t_kernel<<<252, 256, 0, stream>>>(wp, ws);
  sn_tn_kernel<<<6, 256, 0, stream>>>(ws);
  sn_z_kernel<<<1008, 256, 0, stream>>>(wp, ws);
  for (int l = 0; l < 6; l++)
    wscale_kernel<<<(kWSize[l]+255)/256, 256, 0, stream>>>(wp.p[l], ws + WS_OFF_W + kWOff[l],
                                                           kWSize[l], ws + WS_OFF_TN + l, ws + WS_OFF_S2 + l);

  bbox_kernel<<<64, 256, 0, stream>>>(img, sem, bbox);
  transimg_kernel<<<49152, 256, 0, stream>>>(img, sem, bbox, out + OUT_IMG);

  // conv1: images(8,24,256,256) -> (8,64,128,128)   [stencil tile]
  conv3x3_tile<3,3,8,8,0><<<dim3(16,8,8), 256, 0, stream>>>(out + OUT_IMG, ws + WS_OFF_W + kWOff[0],
                                                            bufA, 256, 128);
  inorm_kernel<<<512, 256, 0, stream>>>(bufA, bufB, 16384, 0);
  // conv2 -> (8,128,64,64)
  conv3x3_tile<8,2,16,16,1><<<dim3(4,8,8), 256, 0, stream>>>(bufB, ws + WS_OFF_W + kWOff[1],
                                                             bufA, 128, 64);
  inorm_kernel<<<1024, 256, 0, stream>>>(bufA, bufB, 4096, 0);
  // conv3 -> out_8 (8,256,32,32)
  conv3x3_tile<16,2,32,8,1><<<dim3(4,8,8), 256, 0, stream>>>(bufB, ws + WS_OFF_W + kWOff[2],
                                                             bufA, 64, 32);
  inorm_kernel<<<2048, 256, 0, stream>>>(bufA, bufC, 1024, 0);
  // conv4 -> out_16 (8,512,16,16)   [im2col gemm]
  conv3x3_gemm<2,32,64,4><<<dim3(4,1,64), 256, 0, stream>>>(bufC, ws + WS_OFF_W + kWOff[3], bufA, 32);
  inorm_kernel<<<4096, 256, 0, stream>>>(bufA, bufD, 256, 0);
  // conv5 -> out_32 (8,1024,8,8)
  conv3x3_gemm<2,64,128,3><<<dim3(1,2,64), 256, 0, stream>>>(bufD, ws + WS_OFF_W + kWOff[4], bufA, 16);
  inorm_kernel<<<8192, 64, 0, stream>>>(bufA, bufB, 64, 0);
  // conv6 -> (8,2048,8,8), stride 1
  conv3x3_gemm<1,128,256,3><<<dim3(1,4,64), 256, 0, stream>>>(bufB, ws + WS_OFF_W + kWOff[5], bufA, 8);
  inorm_kernel<<<16384, 64, 0, stream>>>(bufA, out + OUT_X, 64, 1);   // x

  // x_1 -> (8,2048,18,18)
  border_kernel<<<dim3(1,2048,8), 256, 0, stream>>>(gb1, out + OUT_X1, 16);
  conv1x1_gemm<<<dim3(4, 32, 8), 256, 0, stream>>>(bufD, gw1, gb1, out + OUT_X1, 512, 16);
  // x_2 -> (8,2048,34,34)
  border_kernel<<<dim3(1,2048,8), 256, 0, stream>>>(gb2, out + OUT_X2, 32);
  conv1x1_gemm<<<dim3(16, 32, 8), 256, 0, stream>>>(bufC, gw2, gb2, out + OUT_X2, 256, 32);
}